// Round 5
// baseline (35729.904 us; speedup 1.0000x reference)
//
#include <hip/hip_runtime.h>
#include <hip/hip_bf16.h>

// Persistent-kernel seq2seq (enc LSTM -> attn decoder -> CE loss) for MI355X.
// R5: 2 phases per decoder step.
//  P1: gates GEMM with OUTPUT-PROJECTION FOLDED into weights (Vprev fold:
//      gates = e@dWe + h@(dWhh+W2[:,:512]) + attn@W2[:,512:] + bias', where
//      W2 = dWv@outW) + lagged Vnew_{t-1}+tanh reusing the same A-fragments.
//  P2: per-row q (VALU matvec) + SINGLE-PASS online-softmax flash attention
//      over compacted enc_hs + lagged logits/CE (vocab halves per WG).

#define NWG 256
#define NT  256

typedef unsigned short u16;
typedef unsigned int   u32;
typedef unsigned long long u64;
typedef __attribute__((ext_vector_type(4))) float f4;
typedef __attribute__((ext_vector_type(8))) short s8;

constexpr int Bv=128, Lc=512, Le=512, Hd=512, Vc=128;
constexpr int KE=640, KD=1152;

// ---- workspace layout (bytes) ----
constexpr size_t O_WENC = 4096;                                // bf16 [2048][640]
constexpr size_t O_WDEC = O_WENC + (size_t)2048*KE*2;          // bf16 [2048][1152] orig (t=0)
constexpr size_t O_WDF  = O_WDEC + (size_t)2048*KD*2;          // bf16 [2048][1152] folded
constexpr size_t O_ATTW = O_WDF  + (size_t)2048*KD*2;          // bf16 [512][512]
constexpr size_t O_OUTW = O_ATTW + (size_t)512*512*2;          // bf16 [512][1024]
constexpr size_t O_VOCW = O_OUTW + (size_t)512*1024*2;         // bf16 [128][512]
constexpr size_t O_BE   = O_VOCW + (size_t)128*512*2;          // f32[2048]
constexpr size_t O_BD   = O_BE + 8192;                         // f32[2048] orig
constexpr size_t O_BDF  = O_BD + 8192;                         // f32[2048] folded
constexpr size_t O_H    = O_BDF + 8192;                        // bf16 [2][128][512]
constexpr size_t O_TNH  = O_H + (size_t)2*128*512*2;           // bf16 [2][128][512]
constexpr size_t O_PFX  = O_TNH + (size_t)2*128*512*2;         // u32 [128][512]
constexpr size_t O_CNT  = O_PFX + (size_t)128*512*4;           // u32[128]
constexpr size_t O_PMS  = O_CNT + 512;                         // u64 [128][2] (m,s)
constexpr size_t O_PACC = O_PMS + 2048;                        // bf16 [128][2][512]
constexpr size_t O_REC  = O_PACC + (size_t)256*512*2;          // f32 [2][128][2][4]
constexpr size_t O_LOSS = O_REC + (size_t)2*128*2*4*4;         // f32[2]
constexpr size_t O_ENC  = O_LOSS + 256;                        // bf16 [128][512][512]

// ---- LDS ----
constexpr int SM_U     = 64*KD*2;          // 147456 weight slice end
constexpr int SM_BYTES = SM_U + 16384;     // 160 KB

struct P {
  const float *C; const int *Cpad; const int *E; const float *Eemb;
  const float *eWih,*eWhh,*ebih,*ebhh;
  const float *dWih,*dWhh,*dbih,*dbhh;
  const float *attW,*outW,*outb,*vocW,*vocb;
  char* ws; float* out;
};

__device__ inline u16 f2bf(float x){
  u32 u = __float_as_uint(x);
  return (u16)((u + 0x7fffu + ((u>>16)&1u)) >> 16);
}
__device__ inline float bf2f(u16 b){ return __uint_as_float(((u32)b)<<16); }
__device__ inline float sigm(float x){ return 1.f/(1.f+expf(-x)); }
__device__ inline f4 MM(s8 a, s8 b, f4 c){
  return __builtin_amdgcn_mfma_f32_16x16x32_bf16(a, b, c, 0, 0, 0);
}
// device-scope relaxed (cache-bypass) helpers
__device__ inline u64 ld64a(const void* p){
  return __hip_atomic_load((const u64*)p, __ATOMIC_RELAXED, __HIP_MEMORY_SCOPE_AGENT);
}
__device__ inline u32 ld32u(const void* p){
  return __hip_atomic_load((const u32*)p, __ATOMIC_RELAXED, __HIP_MEMORY_SCOPE_AGENT);
}
__device__ inline void st64a(void* p, u64 v){
  __hip_atomic_store((u64*)p, v, __ATOMIC_RELAXED, __HIP_MEMORY_SCOPE_AGENT);
}
__device__ inline void st32a(void* p, u32 v){
  __hip_atomic_store((u32*)p, v, __ATOMIC_RELAXED, __HIP_MEMORY_SCOPE_AGENT);
}
__device__ inline s8 ld16a(const void* p){
  union { u64 q[2]; s8 v; } u;
  u.q[0] = ld64a(p); u.q[1] = ld64a((const char*)p + 8);
  return u.v;
}
__device__ inline s8 cvt8(const float* p){
  f4 u = *(const f4*)p, v = *(const f4*)(p+4);
  s8 r;
  r[0]=(short)f2bf(u[0]); r[1]=(short)f2bf(u[1]); r[2]=(short)f2bf(u[2]); r[3]=(short)f2bf(u[3]);
  r[4]=(short)f2bf(v[0]); r[5]=(short)f2bf(v[1]); r[6]=(short)f2bf(v[2]); r[7]=(short)f2bf(v[3]);
  return r;
}
__device__ inline s8 ldsB(const char* sm, int K, int srow, int k){
  int byte = srow*(K*2) + k*2;
  byte ^= (srow&7)<<4;
  return *(const s8*)(sm + byte);
}
__device__ inline float wredmax(float v){
  #pragma unroll
  for (int m=32;m;m>>=1) v = fmaxf(v, __shfl_xor(v,m,64));
  return v;
}
__device__ inline float wredsum(float v){
  #pragma unroll
  for (int m=32;m;m>>=1) v += __shfl_xor(v,m,64);
  return v;
}
// dot8 + full 64-lane all-reduce (sums the 64 h-slices; result uniform)
__device__ inline float dscore(s8 e, const float* q8){
  float d = bf2f((u16)e[0])*q8[0] + bf2f((u16)e[1])*q8[1]
          + bf2f((u16)e[2])*q8[2] + bf2f((u16)e[3])*q8[3]
          + bf2f((u16)e[4])*q8[4] + bf2f((u16)e[5])*q8[5]
          + bf2f((u16)e[6])*q8[6] + bf2f((u16)e[7])*q8[7];
  #pragma unroll
  for (int mk=1; mk<64; mk<<=1) d += __shfl_xor(d, mk, 64);
  return d;
}

extern "C" __global__ void __launch_bounds__(NT,1) k_main(P p)
{
  extern __shared__ char sm[];
  const int wg = blockIdx.x, tid = threadIdx.x;
  const int gt = wg*NT + tid;
  const int rg = wg & 7, cg = wg >> 3;

  char* ws = p.ws;
  u32*  barAll  = (u32*)ws;
  u32*  flagAll = (u32*)(ws + 128);
  u32*  barRG   = (u32*)(ws + 512 + rg*256);
  u32*  flagRG  = (u32*)(ws + 512 + rg*256 + 128);
  u16*  wenc = (u16*)(ws + O_WENC);
  u16*  wdec = (u16*)(ws + O_WDEC);
  u16*  wdf  = (u16*)(ws + O_WDF);
  u16*  attw = (u16*)(ws + O_ATTW);
  u16*  outw = (u16*)(ws + O_OUTW);
  u16*  vocw = (u16*)(ws + O_VOCW);
  float* be  = (float*)(ws + O_BE);
  float* bd  = (float*)(ws + O_BD);
  float* bdf = (float*)(ws + O_BDF);
  u16*  hbf  = (u16*)(ws + O_H);
  u16*  tnhb = (u16*)(ws + O_TNH);
  u32*  pfx  = (u32*)(ws + O_PFX);
  u32*  cntp = (u32*)(ws + O_CNT);
  u64*  pms  = (u64*)(ws + O_PMS);
  u16*  pacc16 = (u16*)(ws + O_PACC);
  float* rec = (float*)(ws + O_REC);
  float* losp= (float*)(ws + O_LOSS);
  u16*  encc = (u16*)(ws + O_ENC);

  u32 genA = 0, genG = 0;
  auto GBall = [&](){
    genA++;
    __syncthreads();
    if (tid == 0){
      __builtin_amdgcn_fence(__ATOMIC_RELEASE, "agent");
      u32 old = __hip_atomic_fetch_add(barAll, 1u, __ATOMIC_RELAXED, __HIP_MEMORY_SCOPE_AGENT);
      if (old == genA*(u32)NWG - 1u) st32a(flagAll, genA);
      else while (ld32u(flagAll) < genA) __builtin_amdgcn_s_sleep(2);
      __builtin_amdgcn_fence(__ATOMIC_ACQUIRE, "agent");
    }
    __syncthreads();
  };
  auto RGB = [&](){
    genG++;
    __syncthreads();
    if (tid == 0){
      u32 old = __hip_atomic_fetch_add(barRG, 1u, __ATOMIC_RELAXED, __HIP_MEMORY_SCOPE_AGENT);
      if (old == genG*32u - 1u) st32a(flagRG, genG);
      else while (ld32u(flagRG) < genG) __builtin_amdgcn_s_sleep(1);
      __builtin_amdgcn_fence(__ATOMIC_ACQUIRE, "workgroup");
    }
    __syncthreads();
  };

  // ================= phase 0: convert, fold, init =================
  for (int i = gt; i < 2048*KE; i += NWG*NT){
    int row = i / KE, k = i - row*KE;
    float v = (k < 128) ? p.eWih[row*128 + k] : p.eWhh[row*512 + (k-128)];
    wenc[i] = f2bf(v);
  }
  for (int i = gt; i < 2048*KD; i += NWG*NT){
    int row = i / KD, k = i - row*KD;
    float v = (k < 640) ? p.dWih[row*640 + k] : p.dWhh[row*512 + (k-640)];
    wdec[i] = f2bf(v);
  }
  for (int i = gt; i < 512*512;  i += NWG*NT) attw[i] = f2bf(p.attW[i]);
  for (int i = gt; i < 512*1024; i += NWG*NT) outw[i] = f2bf(p.outW[i]);
  for (int i = gt; i < 128*512;  i += NWG*NT) vocw[i] = f2bf(p.vocW[i]);
  for (int i = gt; i < 2048;     i += NWG*NT){ be[i] = p.ebih[i]+p.ebhh[i]; bd[i] = p.dbih[i]+p.dbhh[i]; }
  { u32* hz = (u32*)hbf; for (int i = gt; i < 65536; i += NWG*NT) hz[i] = 0; }
  if (gt == 0){ losp[0] = 0.f; losp[1] = 0.f; }

  // --- W2 = dWv @ outW fold; wdf/bdf build. WG owns 8 gate-rows. ---
  {
    const int g0 = wg*8;
    float* dv = (float*)sm;                      // [8][512] f32
    for (int i = tid; i < 8*512; i += NT)
      dv[i] = p.dWih[(size_t)(g0 + (i>>9))*640 + 128 + (i&511)];
    __syncthreads();
    float wa[8][4];
    #pragma unroll
    for (int r=0;r<8;r++){ wa[r][0]=0;wa[r][1]=0;wa[r][2]=0;wa[r][3]=0; }
    for (int o = 0; o < 512; o++){
      float b0 = p.outW[(size_t)o*1024 + tid];
      float b1 = p.outW[(size_t)o*1024 + 256 + tid];
      float b2 = p.outW[(size_t)o*1024 + 512 + tid];
      float b3 = p.outW[(size_t)o*1024 + 768 + tid];
      #pragma unroll
      for (int r=0;r<8;r++){
        float d = dv[r*512+o];
        wa[r][0] += d*b0; wa[r][1] += d*b1; wa[r][2] += d*b2; wa[r][3] += d*b3;
      }
    }
    #pragma unroll
    for (int r=0;r<8;r++){
      int g = g0 + r;
      #pragma unroll
      for (int j=0;j<4;j++){
        int c = tid + 256*j;
        if (c < 512) wdf[(size_t)g*KD + 128 + c] = f2bf(p.dWhh[(size_t)g*512 + c] + wa[r][j]);
        else         wdf[(size_t)g*KD + 640 + (c-512)] = f2bf(wa[r][j]);
      }
    }
    for (int i = tid; i < 8*128; i += NT){
      int r = i >> 7, k = i & 127;
      wdf[(size_t)(g0+r)*KD + k] = f2bf(p.dWih[(size_t)(g0+r)*640 + k]);
    }
    if (tid < 8){
      int g = g0 + tid;
      float s = p.dbih[g] + p.dbhh[g];
      for (int o = 0; o < 512; o++) s += dv[tid*512+o]*p.outb[o];
      bdf[g] = s;
    }
    __syncthreads();
  }

  if (wg < 128){
    int* padl = (int*)(sm + SM_U);
    for (int i = tid; i < 512; i += NT) padl[i] = p.Cpad[wg*512 + i];
    __syncthreads();
    if (tid == 0){
      u32 run = 0;
      for (int tt = 0; tt < 512; tt++){ pfx[wg*512+tt] = run; if (padl[tt] == 0) run++; }
      cntp[wg] = run;
    }
    __syncthreads();
  }
  GBall();

  const int l  = tid & 63, wv = tid >> 6;
  const int n2 = wv >> 1, k2 = wv & 1;
  const int kl = (l>>4) << 3;
  const int ar = rg*16 + (l&15);
  float cst = 0.f;
  float accN = 0.f, accC = 0.f;

  // ================= encoder =================
  {
    const int chunks = KE/8;
    for (int idx = tid; idx < 64*chunks; idx += NT){
      int s = idx / chunks, cc = idx - s*chunks;
      int grow = (s>>4)*512 + cg*16 + (s&15);
      uint4 v = *(const uint4*)(wenc + (size_t)grow*KE + cc*8);
      int byte = s*(KE*2) + cc*16; byte ^= (s&7)<<4;
      *(uint4*)(sm + byte) = v;
    }
  }
  __syncthreads();

  for (int t = 0; t < Lc; t++){
    const u16* hold = hbf + (t&1)*Bv*Hd;
    u16* hnew       = hbf + ((t+1)&1)*Bv*Hd;
    s8 a[10];
    #pragma unroll
    for (int ks = 0; ks < 10; ks++){
      int k = k2*320 + ks*32 + kl;
      if (k < 128) a[ks] = cvt8(p.C + ((size_t)ar*Lc + t)*Vc + k);
      else         a[ks] = ld16a(hold + (size_t)ar*Hd + (k-128));
    }
    f4 acc0 = {0,0,0,0}, acc1 = {0,0,0,0};
    #pragma unroll
    for (int ks = 0; ks < 10; ks++){
      int k = k2*320 + ks*32 + kl;
      acc0 = MM(a[ks], ldsB(sm, KE, (n2*2+0)*16 + (l&15), k), acc0);
      acc1 = MM(a[ks], ldsB(sm, KE, (n2*2+1)*16 + (l&15), k), acc1);
    }
    float* exch = (float*)(sm + SM_U);
    #pragma unroll
    for (int r = 0; r < 4; r++){
      int row = ((l>>4)<<2) + r;
      exch[((k2*4 + n2*2+0)*16 + row)*16 + (l&15)] = acc0[r];
      exch[((k2*4 + n2*2+1)*16 + row)*16 + (l&15)] = acc1[r];
    }
    __syncthreads();
    {
      int row = tid >> 4, u = tid & 15;
      int gb = cg*16 + u;
      float gi = exch[((0)*16+row)*16+u] + exch[((4)*16+row)*16+u] + be[0*512+gb];
      float gf = exch[((1)*16+row)*16+u] + exch[((5)*16+row)*16+u] + be[1*512+gb];
      float gg = exch[((2)*16+row)*16+u] + exch[((6)*16+row)*16+u] + be[2*512+gb];
      float go = exch[((3)*16+row)*16+u] + exch[((7)*16+row)*16+u] + be[3*512+gb];
      float fi = sigm(gi), ff = sigm(gf), fg = tanhf(gg), fo = sigm(go);
      cst = ff*cst + fi*fg;
      float hn = fo * tanhf(cst);
      int b = rg*16 + row;
      u32 hb = f2bf(hn);
      u32 nb = __shfl_xor((int)hb, 1, 64);
      if ((tid & 1) == 0){
        u32 pk = hb | (nb << 16);
        st32a(hnew + (size_t)b*Hd + gb, pk);
        if (p.Cpad[b*Lc + t] == 0){
          u32 pos = pfx[b*Lc + t];
          st32a(encc + ((size_t)b*Lc + pos)*Hd + gb, pk);
        }
      }
    }
    RGB();
  }

  GBall();   // flush+inv once: decoder reads encc/pfx/wdf CACHED safely

  // ================= decoder =================
  { // stage FOLDED weight slice to LDS
    const int chunks = KD/8;
    for (int idx = tid; idx < 64*chunks; idx += NT){
      int s = idx / chunks, cc = idx - s*chunks;
      int grow = (s>>4)*512 + cg*16 + (s&15);
      uint4 v = *(const uint4*)(wdf + (size_t)grow*KD + cc*8);
      int byte = s*(KD*2) + cc*16; byte ^= (s&7)<<4;
      *(uint4*)(sm + byte) = v;
    }
  }
  __syncthreads();

  float* exch = (float*)(sm + SM_U);          // [8][16][16] f32 (8 KB)
  float* vex  = (float*)(sm + SM_U + 8192);   // [4][16][16] f32 (4 KB)
  float* sc2  = (float*)(sm + SM_U + 12288);  // [16][2] f32

  // CE record for step tl (this WG's vocab half of its row)
  auto CEREC = [&](int tl, int row, int half){
    u32* th16 = (u32*)(sm + SM_U + 12416);    // raw bf16x2 [256]
    float* lgp = (float*)(sm + SM_U + 13440); // [4][64]
    float* lgh = (float*)(sm + SM_U + 14464); // [64]
    const u16* tb = tnhb + (size_t)(tl&1)*Bv*Hd + (size_t)row*Hd;
    th16[tid & 255] = ld32u(tb + 2*tid);
    __syncthreads();
    {
      int v = tid & 63, ksl = tid >> 6;
      int gv = half*64 + v;
      const u16* wp = vocw + (size_t)gv*Hd + ksl*128;
      const u16* hp = (const u16*)th16 + ksl*128;
      float acc = 0.f;
      #pragma unroll 4
      for (int j = 0; j < 16; j++){
        s8 wv8 = *(const s8*)(wp + j*8);
        #pragma unroll
        for (int q = 0; q < 8; q++) acc += bf2f((u16)wv8[q]) * bf2f(hp[j*8+q]);
      }
      lgp[ksl*64 + v] = acc;
    }
    __syncthreads();
    if (tid < 64){
      int gv = half*64 + tid;
      float lv = lgp[tid] + lgp[64+tid] + lgp[128+tid] + lgp[192+tid] + p.vocb[gv];
      lgh[tid] = lv;
      float m = wredmax(lv);
      float s = wredsum(expf(lv - m));
      if (tid == 0){
        int tgt = p.E[row*Le + tl + 1];
        float tlg = (tgt >= half*64 && tgt < half*64+64) ? lgh[tgt - half*64] : 0.f;
        float* rp = rec + ((size_t)(tl&1)*256 + row*2 + half)*4;
        union { u64 q; float f[2]; } pk; pk.f[0]=m; pk.f[1]=s;
        st64a(rp, pk.q);
        st32a(rp+2, __float_as_uint(tlg));
      }
    }
    __syncthreads();
  };
  // combine both halves' records for step tl (tid0 of half0 WG)
  auto COMB = [&](int tl, int row){
    int tgt = p.E[row*Le + tl + 1];
    if (tgt != 0){
      const float* rp = rec + ((size_t)(tl&1)*256 + row*2)*4;
      union { u64 q; float f[2]; } a, b;
      a.q = ld64a(rp); b.q = ld64a(rp+4);
      float tA = __uint_as_float(ld32u(rp+2)), tB = __uint_as_float(ld32u(rp+6));
      float M = fmaxf(a.f[0], b.f[0]);
      float S = a.f[1]*expf(a.f[0]-M) + b.f[1]*expf(b.f[0]-M);
      accN += logf(S) + M - (tA + tB);
      accC += 1.f;
    }
  };

  for (int t = 0; t < Le-1; t++){
    const u16* hold = hbf + (t&1)*Bv*Hd;
    u16* hnew       = hbf + ((t+1)&1)*Bv*Hd;

    // ======== P1: gates (+ lagged Vnew_{t-1}) ========
    if (t == 0){
      // Vprev = 0: original weights, B from GLOBAL wdec
      s8 a[10];
      #pragma unroll
      for (int ks = 0; ks < 10; ks++){
        int ke = (k2==0) ? ((ks<4) ? ks*32+kl : 640 + (ks-4)*32 + kl)
                         : (832 + ks*32 + kl);
        if (ke < 128) a[ks] = cvt8(p.Eemb + ((size_t)ar*Le + 0)*Vc + ke);
        else          a[ks] = ld16a(hold + (size_t)ar*Hd + (ke-640));
      }
      f4 acc0 = {0,0,0,0}, acc1 = {0,0,0,0};
      #pragma unroll
      for (int ks = 0; ks < 10; ks++){
        int ke = (k2==0) ? ((ks<4) ? ks*32+kl : 640 + (ks-4)*32 + kl)
                         : (832 + ks*32 + kl);
        int g0r = (n2*2+0)*512 + cg*16 + (l&15);
        int g1r = (n2*2+1)*512 + cg*16 + (l&15);
        acc0 = MM(a[ks], *(const s8*)(wdec + (size_t)g0r*KD + ke), acc0);
        acc1 = MM(a[ks], *(const s8*)(wdec + (size_t)g1r*KD + ke), acc1);
      }
      #pragma unroll
      for (int r = 0; r < 4; r++){
        int row = ((l>>4)<<2) + r;
        exch[((k2*4 + n2*2+0)*16 + row)*16 + (l&15)] = acc0[r];
        exch[((k2*4 + n2*2+1)*16 + row)*16 + (l&15)] = acc1[r];
      }
      __syncthreads();
      {
        int row = tid >> 4, u = tid & 15;
        int gb = cg*16 + u;
        float gi = exch[((0)*16+row)*16+u] + exch[((4)*16+row)*16+u] + bd[0*512+gb];
        float gf = exch[((1)*16+row)*16+u] + exch[((5)*16+row)*16+u] + bd[1*512+gb];
        float gg = exch[((2)*16+row)*16+u] + exch[((6)*16+row)*16+u] + bd[2*512+gb];
        float go = exch[((3)*16+row)*16+u] + exch[((7)*16+row)*16+u] + bd[3*512+gb];
        float fi = sigm(gi), ff = sigm(gf), fg = tanhf(gg), fo = sigm(go);
        cst = ff*cst + fi*fg;
        float hn = fo * tanhf(cst);
        u32 hb = f2bf(hn);
        u32 nb = __shfl_xor((int)hb, 1, 64);
        if ((tid & 1) == 0)
          st32a(hnew + (size_t)(rg*16+(tid>>4))*Hd + gb, hb | (nb << 16));
      }
    } else {
      // softmax combine scales per row (from step t-1 partials)
      if (tid < 16){
        union { u64 q; float f[2]; } uA, uB;
        uA.q = ld64a(pms + (rg*16+tid)*2 + 0);
        uB.q = ld64a(pms + (rg*16+tid)*2 + 1);
        float M = fmaxf(uA.f[0], uB.f[0]);
        float eA = (uA.f[0] > -1e29f) ? expf(uA.f[0]-M) : 0.f;
        float eB = (uB.f[0] > -1e29f) ? expf(uB.f[0]-M) : 0.f;
        float den = uA.f[1]*eA + uB.f[1]*eB;
        sc2[tid*2]   = eA/den;
        sc2[tid*2+1] = eB/den;
      }
      __syncthreads();
      const float scA = sc2[(l&15)*2], scB = sc2[(l&15)*2+1];
      const u16* pA = pacc16 + (size_t)(ar*2+0)*Hd;
      const u16* pB = pacc16 + (size_t)(ar*2+1)*Hd;
      s8 a[18];
      #pragma unroll
      for (int ks = 0; ks < 18; ks++){
        int k = k2*576 + ks*32 + kl;
        if (k < 128)      a[ks] = cvt8(p.Eemb + ((size_t)ar*Le + t)*Vc + k);
        else if (k < 640) a[ks] = ld16a(hold + (size_t)ar*Hd + (k-128));
        else {
          s8 va = ld16a(pA + (k-640));
          s8 vb = ld16a(pB + (k-640));
          s8 r;
          #pragma unroll
          for (int j = 0; j < 8; j++)
            r[j] = (short)f2bf(scA*bf2f((u16)va[j]) + scB*bf2f((u16)vb[j]));
          a[ks] = r;
        }
      }
      f4 acc0 = {0,0,0,0}, acc1 = {0,0,0,0};
      #pragma unroll
      for (int ks = 0; ks < 18; ks++){
        int k = k2*576 + ks*32 + kl;
        acc0 = MM(a[ks], ldsB(sm, KD, (n2*2+0)*16 + (l&15), k), acc0);
        acc1 = MM(a[ks], ldsB(sm, KD, (n2*2+1)*16 + (l&15), k), acc1);
      }
      // lagged Vnew_{t-1}: A-fragments (k>=128) are exactly U_{t-1}=[h,attn]
      f4 vac = {0,0,0,0};
      const int colc = cg*16 + (l&15);
      #pragma unroll
      for (int ks = 0; ks < 18; ks++){
        int ck = k2*18 + ks - 4;                  // kv chunk = (k-128)/32
        if (ck >= 0 && ((ck & 1) == n2))
          vac = MM(a[ks], *(const s8*)(outw + (size_t)colc*1024 + ck*32 + kl), vac);
      }
      #pragma unroll
      for (int r = 0; r < 4; r++){
        int row = ((l>>4)<<2) + r;
        exch[((k2*4 + n2*2+0)*16 + row)*16 + (l&15)] = acc0[r];
        exch[((k2*4 + n2*2+1)*16 + row)*16 + (l&15)] = acc1[r];
        vex[wv*256 + row*16 + (l&15)] = vac[r];
      }
      __syncthreads();
      {
        int row = tid >> 4, u = tid & 15;
        int gb = cg*16 + u;
        float gi = exch[((0)*16+row)*16+u] + exch[((4)*16+row)*16+u] + bdf[0*512+gb];
        float gf = exch[((1)*16+row)*16+u] + exch[((5)*16+row)*16+u] + bdf[1*512+gb];
        float gg = exch[((2)*16+row)*16+u] + exch[((6)*16+row)*16+u] + bdf[2*512+gb];
        float go = exch[((3)*16+row)*16+u] + exch[((7)*16+row)*16+u] + bdf[3*512+gb];
        float fi = sigm(gi), ff = sigm(gf), fg = tanhf(gg), fo = sigm(go);
        cst = ff*cst + fi*fg;
        float hn = fo * tanhf(cst);
        u32 hb = f2bf(hn);
        u32 nb = __shfl_xor((int)hb, 1, 64);
        if ((tid & 1) == 0)
          st32a(hnew + (size_t)(rg*16+row)*Hd + gb, hb | (nb << 16));
        // Vnew_{t-1} finalize -> tanh -> tnhb[(t-1)&1]
        float v = vex[row*16+u] + vex[256+row*16+u] + vex[512+row*16+u]
                + vex[768+row*16+u] + p.outb[gb];
        u32 tb2 = f2bf(tanhf(v));
        u32 tn2 = __shfl_xor((int)tb2, 1, 64);
        if ((tid & 1) == 0){
          u16* tnw = tnhb + (size_t)((t-1)&1)*Bv*Hd;
          st32a(tnw + (size_t)(rg*16+row)*Hd + gb, tb2 | (tn2 << 16));
        }
      }
    }
    RGB();

    // ======== P2: q + single-pass flash attention + lagged CE ========
    {
      const int row = rg*16 + (cg >> 1), half = cg & 1;
      const int cn = (int)cntp[row], c2 = cn >> 1;
      const int st = half ? c2 : 0, en = half ? cn : c2, n = en - st;
      float* hq = (float*)(sm + SM_U);            // f32[512]
      float* qv = (float*)(sm + SM_U + 2048);     // f32[512]
      float* pm4 = (float*)(sm + SM_U + 4096);    // [4]
      float* ps4 = (float*)(sm + SM_U + 4128);    // [4]
      float* part= (float*)(sm + SM_U + 4224);    // [4][512]
      {
        u32 hw = ld32u(hnew + (size_t)row*Hd + 2*tid);
        hq[2*tid]   = bf2f((u16)(hw & 0xffffu));
        hq[2*tid+1] = bf2f((u16)(hw >> 16));
      }
      __syncthreads();
      // q[j] for j = 2*tid, 2*tid+1
      {
        int j0 = 2*tid;
        float q0 = 0.f, q1 = 0.f;
        const u16* w0 = attw + (size_t)j0*Hd;
        const u16* w1 = w0 + Hd;
        #pragma unroll 4
        for (int kk = 0; kk < 64; kk++){
          s8 a0 = *(const s8*)(w0 + kk*8);
          s8 a1 = *(const s8*)(w1 + kk*8);
          #pragma unroll
          for (int q = 0; q < 8; q++){
            float h = hq[kk*8+q];
            q0 += bf2f((u16)a0[q]) * h;
            q1 += bf2f((u16)a1[q]) * h;
          }
        }
        qv[j0] = q0; qv[j0+1] = q1;
      }
      __syncthreads();
      float q8[8];
      #pragma unroll
      for (int j = 0; j < 8; j++) q8[j] = qv[l*8 + j];
      // online flash over this WG's positions, per wave
      float m = -1e30f, s = 0.f;
      float acc[8] = {0,0,0,0,0,0,0,0};
      const u16* eb = encc + ((size_t)row*Lc + st)*Hd + l*8;
      int ii = wv;
      for (; ii + 12 < n; ii += 16){
        s8 e0 = *(const s8*)(eb + (size_t)(ii   )*Hd);
        s8 e1 = *(const s8*)(eb + (size_t)(ii+ 4)*Hd);
        s8 e2 = *(const s8*)(eb + (size_t)(ii+ 8)*Hd);
        s8 e3 = *(const s8*)(eb + (size_t)(ii+12)*Hd);
        float s0 = dscore(e0, q8), s1 = dscore(e1, q8);
        float s2 = dscore(e2, q8), s3 = dscore(e3, q8);
        float tm = fmaxf(fmaxf(s0,s1), fmaxf(s2,s3));
        if (tm > m){
          float fac = expf(m - tm);     // m=-1e30 first time -> 0
          s *= fac;
          #pragma unroll
          for (int j=0;j<8;j++) acc[j] *= fac;
          m = tm;
        }
        float w0 = expf(s0-m), w1 = expf(s1-m), w2 = expf(s2-m), w3 = expf(s3-m);
        s += w0+w1+w2+w3;
        #pragma unroll
        for (int j=0;j<8;j++)
          acc[j] += w0*bf2f((u16)e0[j]) + w1*bf2f((u16)e1[j])
                  + w2*bf2f((u16)e2[j]) + w3*bf2f((u16)e3[j]);
      }
      for (; ii < n; ii += 4){
        s8 e0 = *(const s8*)(eb + (size_t)ii*Hd);
        float s0 = dscore(e0, q8);
        if (s0 > m){
          float fac = expf(m - s0);
          s *= fac;
          #pragma unroll
          for (int j=0;j<8;j++) acc[j] *= fac;
          m = s0;
        }
        float w0 = expf(s0-m);
        s += w0;
        #pragma unroll
        for (int j=0;j<8;j++) acc[j] += w0*bf2f((u16)e0[j]);
      }
      if (l == 0){ pm4[wv] = m; ps4[wv] = s; }
      { f4 v0 = {acc[0],acc[1],acc[2],acc[3]}, v1 = {acc[4],acc[5],acc[6],acc[7]};
        *(f4*)(part + wv*512 + l*8)     = v0;
        *(f4*)(part + wv*512 + l*8 + 4) = v1; }
      __syncthreads();
      {
        float M = fmaxf(fmaxf(pm4[0],pm4[1]), fmaxf(pm4[2],pm4[3]));
        float f0 = (pm4[0] > -1e29f) ? expf(pm4[0]-M) : 0.f;
        float f1 = (pm4[1] > -1e29f) ? expf(pm4[1]-M) : 0.f;
        float f2 = (pm4[2] > -1e29f) ? expf(pm4[2]-M) : 0.f;
        float f3 = (pm4[3] > -1e29f) ? expf(pm4[3]-M) : 0.f;
        float S = ps4[0]*f0 + ps4[1]*f1 + ps4[2]*f2 + ps4[3]*f3;
        int h0 = 2*tid;
        float a0 = part[h0]*f0 + part[512+h0]*f1 + part[1024+h0]*f2 + part[1536+h0]*f3;
        float a1 = part[h0+1]*f0 + part[512+h0+1]*f1 + part[1024+h0+1]*f2 + part[1536+h0+1]*f3;
        st32a(pacc16 + (size_t)(row*2+half)*Hd + h0, (u32)f2bf(a0) | ((u32)f2bf(a1) << 16));
        if (tid == 0){
          union { u64 q; float f[2]; } pk; pk.f[0]=M; pk.f[1]=S;
          st64a(pms + row*2 + half, pk.q);
        }
      }
      __syncthreads();
      if (t >= 1) CEREC(t-1, row, half);
      if (t >= 2 && half == 0 && tid == 0) COMB(t-2, row);
    }
    RGB();
  }

  // ================= epilogue =================
  const int TL = Le-2;   // 510
  // E1: Vnew_{510} + tanh (all WGs)
  {
    if (tid < 16){
      union { u64 q; float f[2]; } uA, uB;
      uA.q = ld64a(pms + (rg*16+tid)*2 + 0);
      uB.q = ld64a(pms + (rg*16+tid)*2 + 1);
      float M = fmaxf(uA.f[0], uB.f[0]);
      float eA = (uA.f[0] > -1e29f) ? expf(uA.f[0]-M) : 0.f;
      float eB = (uB.f[0] > -1e29f) ? expf(uB.f[0]-M) : 0.f;
      float den = uA.f[1]*eA + uB.f[1]*eB;
      sc2[tid*2]   = eA/den;
      sc2[tid*2+1] = eB/den;
    }
    __syncthreads();
    const float scA = sc2[(l&15)*2], scB = sc2[(l&15)*2+1];
    const u16* h5 = hbf + (size_t)((TL+1)&1)*Bv*Hd;
    const u16* pA = pacc16 + (size_t)(ar*2+0)*Hd;
    const u16* pB = pacc16 + (size_t)(ar*2+1)*Hd;
    const int colc = cg*16 + (l&15);
    f4 vac = {0,0,0,0};
    #pragma unroll
    for (int j = 0; j < 8; j++){
      int kv = k2*16 + j*2 + n2;
      s8 af;
      if (kv < 16) af = ld16a(h5 + (size_t)ar*Hd + kv*32 + kl);
      else {
        s8 va = ld16a(pA + (kv-16)*32 + kl);
        s8 vb = ld16a(pB + (kv-16)*32 + kl);
        #pragma unroll
        for (int q = 0; q < 8; q++)
          af[q] = (short)f2bf(scA*bf2f((u16)va[q]) + scB*bf2f((u16)vb[q]));
      }
      vac = MM(af, *(const s8*)(outw + (size_t)colc*1024 + kv*32 + kl), vac);
    }
    #pragma unroll
    for (int r = 0; r < 4; r++)
      vex[wv*256 + (((l>>4)<<2)+r)*16 + (l&15)] = vac[r];
    __syncthreads();
    {
      int row = tid >> 4, u = tid & 15;
      int gb = cg*16 + u;
      float v = vex[row*16+u] + vex[256+row*16+u] + vex[512+row*16+u]
              + vex[768+row*16+u] + p.outb[gb];
      u32 tb2 = f2bf(tanhf(v));
      u32 tn2 = __shfl_xor((int)tb2, 1, 64);
      if ((tid & 1) == 0){
        u16* tnw = tnhb + (size_t)(TL&1)*Bv*Hd;
        st32a(tnw + (size_t)(rg*16+row)*Hd + gb, tb2 | (tn2 << 16));
      }
    }
  }
  RGB();
  // E2: CE record for step 510 + combine 509
  {
    const int row = rg*16 + (cg >> 1), half = cg & 1;
    CEREC(TL, row, half);
    if (half == 0 && tid == 0) COMB(TL-1, row);
  }
  RGB();
  // E3: combine step 510, then accumulate loss
  {
    const int row = rg*16 + (cg >> 1), half = cg & 1;
    if (half == 0 && tid == 0){
      COMB(TL, row);
      atomicAdd(losp + 0, accN);
      atomicAdd(losp + 1, accC);
    }
  }
  GBall();
  if (wg == 0 && tid == 0) p.out[0] = losp[0] / fmaxf(losp[1], 1.f);
}

extern "C" void kernel_launch(void* const* d_in, const int* in_sizes, int n_in,
                              void* d_out, int out_size, void* d_ws, size_t ws_size,
                              hipStream_t stream)
{
  hipFuncSetAttribute(reinterpret_cast<const void*>(k_main),
                      hipFuncAttributeMaxDynamicSharedMemorySize, SM_BYTES);
  hipMemsetAsync(d_ws, 0, 4096, stream);

  P prm;
  prm.C    = (const float*)d_in[0];
  prm.Cpad = (const int*)  d_in[1];
  prm.E    = (const int*)  d_in[2];
  prm.Eemb = (const float*)d_in[3];
  prm.eWih = (const float*)d_in[4];
  prm.eWhh = (const float*)d_in[5];
  prm.ebih = (const float*)d_in[6];
  prm.ebhh = (const float*)d_in[7];
  prm.dWih = (const float*)d_in[8];
  prm.dWhh = (const float*)d_in[9];
  prm.dbih = (const float*)d_in[10];
  prm.dbhh = (const float*)d_in[11];
  prm.attW = (const float*)d_in[12];
  prm.outW = (const float*)d_in[13];
  prm.outb = (const float*)d_in[14];
  prm.vocW = (const float*)d_in[15];
  prm.vocb = (const float*)d_in[16];
  prm.ws   = (char*)d_ws;
  prm.out  = (float*)d_out;

  k_main<<<dim3(NWG), dim3(NT), SM_BYTES, stream>>>(prm);
}

// Round 6
// 22746.207 us; speedup vs baseline: 1.5708x; 1.5708x over previous
//
#include <hip/hip_runtime.h>
#include <hip/hip_bf16.h>

// Persistent-kernel seq2seq (enc LSTM -> attn decoder -> CE loss) for MI355X.
// R6: enc_hs lives in LDS (128KB/CU, private, zero-reuse data) while GEMM
// weights stream from L2/MALL (shared, broadcast-friendly). 3 phases/step:
//  P1 folded gates (B from global) + lagged Vnew; P2 col-split q + lagged CE;
//  P3 two-pass flash attention from LDS-resident enc_hs (global overflow).

#define NWG 256
#define NT  256

typedef unsigned short u16;
typedef unsigned int   u32;
typedef unsigned long long u64;
typedef __attribute__((ext_vector_type(4))) float f4;
typedef __attribute__((ext_vector_type(8))) short s8;

constexpr int Bv=128, Lc=512, Le=512, Hd=512, Vc=128;
constexpr int KE=640, KD=1152;
constexpr int CAP = 144;                       // LDS-resident positions per WG

// ---- workspace layout (bytes) ----
constexpr size_t O_WENC = 4096;                                // bf16 [2048][640]
constexpr size_t O_WDEC = O_WENC + (size_t)2048*KE*2;          // bf16 [2048][1152] orig (t=0)
constexpr size_t O_WDF  = O_WDEC + (size_t)2048*KD*2;          // bf16 [2048][1152] folded
constexpr size_t O_ATTW = O_WDF  + (size_t)2048*KD*2;          // bf16 [512][512]
constexpr size_t O_OUTW = O_ATTW + (size_t)512*512*2;          // bf16 [512][1024]
constexpr size_t O_VOCW = O_OUTW + (size_t)512*1024*2;         // bf16 [128][512]
constexpr size_t O_BE   = O_VOCW + (size_t)128*512*2;          // f32[2048]
constexpr size_t O_BD   = O_BE + 8192;                         // f32[2048] orig
constexpr size_t O_BDF  = O_BD + 8192;                         // f32[2048] folded
constexpr size_t O_H    = O_BDF + 8192;                        // bf16 [2][128][512]
constexpr size_t O_TNH  = O_H + (size_t)2*128*512*2;           // bf16 [2][128][512]
constexpr size_t O_Q    = O_TNH + (size_t)2*128*512*2;         // f32 [128][512]
constexpr size_t O_PFX  = O_Q + (size_t)128*512*4;             // u32 [128][512]
constexpr size_t O_CNT  = O_PFX + (size_t)128*512*4;           // u32[128]
constexpr size_t O_PMS  = O_CNT + 512;                         // u64 [128][2] (m,s)
constexpr size_t O_PACC = O_PMS + 2048;                        // bf16 [128][2][512]
constexpr size_t O_REC  = O_PACC + (size_t)256*512*2;          // f32 [2][128][2][4]
constexpr size_t O_LOSS = O_REC + (size_t)2*128*2*4*4;         // f32[2]
constexpr size_t O_ENC  = O_LOSS + 256;                        // bf16 [128][512][512]

// ---- LDS: [0, CAP*1024) = enc_hs slice; [SC, SC+16K) = phase scratch ----
constexpr int SC       = CAP*1024;             // 147456
constexpr int SM_BYTES = SC + 16384;           // 163840 (160 KB)

struct P {
  const float *C; const int *Cpad; const int *E; const float *Eemb;
  const float *eWih,*eWhh,*ebih,*ebhh;
  const float *dWih,*dWhh,*dbih,*dbhh;
  const float *attW,*outW,*outb,*vocW,*vocb;
  char* ws; float* out;
};

__device__ inline u16 f2bf(float x){
  u32 u = __float_as_uint(x);
  return (u16)((u + 0x7fffu + ((u>>16)&1u)) >> 16);
}
__device__ inline float bf2f(u16 b){ return __uint_as_float(((u32)b)<<16); }
__device__ inline float sigm(float x){ return 1.f/(1.f+expf(-x)); }
__device__ inline f4 MM(s8 a, s8 b, f4 c){
  return __builtin_amdgcn_mfma_f32_16x16x32_bf16(a, b, c, 0, 0, 0);
}
// device-scope relaxed (cache-bypass) helpers
__device__ inline u64 ld64a(const void* p){
  return __hip_atomic_load((const u64*)p, __ATOMIC_RELAXED, __HIP_MEMORY_SCOPE_AGENT);
}
__device__ inline u32 ld32u(const void* p){
  return __hip_atomic_load((const u32*)p, __ATOMIC_RELAXED, __HIP_MEMORY_SCOPE_AGENT);
}
__device__ inline void st64a(void* p, u64 v){
  __hip_atomic_store((u64*)p, v, __ATOMIC_RELAXED, __HIP_MEMORY_SCOPE_AGENT);
}
__device__ inline void st32a(void* p, u32 v){
  __hip_atomic_store((u32*)p, v, __ATOMIC_RELAXED, __HIP_MEMORY_SCOPE_AGENT);
}
__device__ inline s8 ld16a(const void* p){
  union { u64 q[2]; s8 v; } u;
  u.q[0] = ld64a(p); u.q[1] = ld64a((const char*)p + 8);
  return u.v;
}
__device__ inline s8 cvt8(const float* p){
  f4 u = *(const f4*)p, v = *(const f4*)(p+4);
  s8 r;
  r[0]=(short)f2bf(u[0]); r[1]=(short)f2bf(u[1]); r[2]=(short)f2bf(u[2]); r[3]=(short)f2bf(u[3]);
  r[4]=(short)f2bf(v[0]); r[5]=(short)f2bf(v[1]); r[6]=(short)f2bf(v[2]); r[7]=(short)f2bf(v[3]);
  return r;
}
__device__ inline float wredmax(float v){
  #pragma unroll
  for (int m=32;m;m>>=1) v = fmaxf(v, __shfl_xor(v,m,64));
  return v;
}
__device__ inline float wredsum(float v){
  #pragma unroll
  for (int m=32;m;m>>=1) v += __shfl_xor(v,m,64);
  return v;
}

extern "C" __global__ void __launch_bounds__(NT,1) k_main(P p)
{
  extern __shared__ char sm[];
  const int wg = blockIdx.x, tid = threadIdx.x;
  const int gt = wg*NT + tid;
  const int rg = wg & 7, cg = wg >> 3;

  char* ws = p.ws;
  u32*  barAll  = (u32*)ws;
  u32*  flagAll = (u32*)(ws + 128);
  u32*  barRG   = (u32*)(ws + 512 + rg*256);
  u32*  flagRG  = (u32*)(ws + 512 + rg*256 + 128);
  u16*  wenc = (u16*)(ws + O_WENC);
  u16*  wdec = (u16*)(ws + O_WDEC);
  u16*  wdf  = (u16*)(ws + O_WDF);
  u16*  attw = (u16*)(ws + O_ATTW);
  u16*  outw = (u16*)(ws + O_OUTW);
  u16*  vocw = (u16*)(ws + O_VOCW);
  float* be  = (float*)(ws + O_BE);
  float* bd  = (float*)(ws + O_BD);
  float* bdf = (float*)(ws + O_BDF);
  u16*  hbf  = (u16*)(ws + O_H);
  u16*  tnhb = (u16*)(ws + O_TNH);
  float* qg  = (float*)(ws + O_Q);
  u32*  pfx  = (u32*)(ws + O_PFX);
  u32*  cntp = (u32*)(ws + O_CNT);
  u64*  pms  = (u64*)(ws + O_PMS);
  u16*  pacc16 = (u16*)(ws + O_PACC);
  float* rec = (float*)(ws + O_REC);
  float* losp= (float*)(ws + O_LOSS);
  u16*  encc = (u16*)(ws + O_ENC);

  u32 genA = 0, genG = 0;
  auto GBall = [&](){
    genA++;
    __syncthreads();
    if (tid == 0){
      __builtin_amdgcn_fence(__ATOMIC_RELEASE, "agent");
      u32 old = __hip_atomic_fetch_add(barAll, 1u, __ATOMIC_RELAXED, __HIP_MEMORY_SCOPE_AGENT);
      if (old == genA*(u32)NWG - 1u) st32a(flagAll, genA);
      else while (ld32u(flagAll) < genA) __builtin_amdgcn_s_sleep(2);
      __builtin_amdgcn_fence(__ATOMIC_ACQUIRE, "agent");
    }
    __syncthreads();
  };
  auto RGB = [&](){
    genG++;
    __syncthreads();
    if (tid == 0){
      u32 old = __hip_atomic_fetch_add(barRG, 1u, __ATOMIC_RELAXED, __HIP_MEMORY_SCOPE_AGENT);
      if (old == genG*32u - 1u) st32a(flagRG, genG);
      else while (ld32u(flagRG) < genG) __builtin_amdgcn_s_sleep(1);
      __builtin_amdgcn_fence(__ATOMIC_ACQUIRE, "workgroup");
    }
    __syncthreads();
  };

  // ================= phase 0: convert, fold, init =================
  for (int i = gt; i < 2048*KE; i += NWG*NT){
    int row = i / KE, k = i - row*KE;
    float v = (k < 128) ? p.eWih[row*128 + k] : p.eWhh[row*512 + (k-128)];
    wenc[i] = f2bf(v);
  }
  for (int i = gt; i < 2048*KD; i += NWG*NT){
    int row = i / KD, k = i - row*KD;
    float v = (k < 640) ? p.dWih[row*640 + k] : p.dWhh[row*512 + (k-640)];
    wdec[i] = f2bf(v);
  }
  for (int i = gt; i < 512*512;  i += NWG*NT) attw[i] = f2bf(p.attW[i]);
  for (int i = gt; i < 512*1024; i += NWG*NT) outw[i] = f2bf(p.outW[i]);
  for (int i = gt; i < 128*512;  i += NWG*NT) vocw[i] = f2bf(p.vocW[i]);
  for (int i = gt; i < 2048;     i += NWG*NT){ be[i] = p.ebih[i]+p.ebhh[i]; bd[i] = p.dbih[i]+p.dbhh[i]; }
  { u32* hz = (u32*)hbf; for (int i = gt; i < 65536; i += NWG*NT) hz[i] = 0; }
  if (gt == 0){ losp[0] = 0.f; losp[1] = 0.f; }

  // --- W2 = dWv @ outW fold; wdf/bdf build. WG owns 8 gate-rows. ---
  {
    const int g0 = wg*8;
    float* dv = (float*)sm;                      // [8][512] f32 (enc_hs region, pre-encoder)
    for (int i = tid; i < 8*512; i += NT)
      dv[i] = p.dWih[(size_t)(g0 + (i>>9))*640 + 128 + (i&511)];
    __syncthreads();
    float wa[8][4];
    #pragma unroll
    for (int r=0;r<8;r++){ wa[r][0]=0;wa[r][1]=0;wa[r][2]=0;wa[r][3]=0; }
    for (int o = 0; o < 512; o++){
      float b0 = p.outW[(size_t)o*1024 + tid];
      float b1 = p.outW[(size_t)o*1024 + 256 + tid];
      float b2 = p.outW[(size_t)o*1024 + 512 + tid];
      float b3 = p.outW[(size_t)o*1024 + 768 + tid];
      #pragma unroll
      for (int r=0;r<8;r++){
        float d = dv[r*512+o];
        wa[r][0] += d*b0; wa[r][1] += d*b1; wa[r][2] += d*b2; wa[r][3] += d*b3;
      }
    }
    #pragma unroll
    for (int r=0;r<8;r++){
      int g = g0 + r;
      #pragma unroll
      for (int j=0;j<4;j++){
        int c = tid + 256*j;
        if (c < 512) wdf[(size_t)g*KD + 128 + c] = f2bf(p.dWhh[(size_t)g*512 + c] + wa[r][j]);
        else         wdf[(size_t)g*KD + 640 + (c-512)] = f2bf(wa[r][j]);
      }
    }
    for (int i = tid; i < 8*128; i += NT){
      int r = i >> 7, k = i & 127;
      wdf[(size_t)(g0+r)*KD + k] = f2bf(p.dWih[(size_t)(g0+r)*640 + k]);
    }
    if (tid < 8){
      int g = g0 + tid;
      float s = p.dbih[g] + p.dbhh[g];
      for (int o = 0; o < 512; o++) s += dv[tid*512+o]*p.outb[o];
      bdf[g] = s;
    }
    __syncthreads();
  }

  if (wg < 128){
    int* padl = (int*)(sm + SC);
    for (int i = tid; i < 512; i += NT) padl[i] = p.Cpad[wg*512 + i];
    __syncthreads();
    if (tid == 0){
      u32 run = 0;
      for (int tt = 0; tt < 512; tt++){ pfx[wg*512+tt] = run; if (padl[tt] == 0) run++; }
      cntp[wg] = run;
    }
    __syncthreads();
  }
  GBall();

  const int l  = tid & 63, wv = tid >> 6;
  const int n2 = wv >> 1, k2 = wv & 1;
  const int kl = (l>>4) << 3;
  const int ar = rg*16 + (l&15);
  float cst = 0.f;
  float accN = 0.f, accC = 0.f;

  // attention ownership: 2 WGs per batch row
  const int rowA = rg*16 + (cg >> 1), halfA = cg & 1;
  const int cnA = (int)cntp[rowA], c2A = cnA >> 1;
  const int loA = halfA ? c2A : 0;
  const int mynA = (halfA ? cnA : c2A) - loA;
  const int ncapA = mynA < CAP ? mynA : CAP;
  u16* eL = (u16*)sm;   // LDS enc_hs slice [CAP][512] bf16

  // CE record for step tl (this WG's vocab half of its row)
  auto CEREC = [&](int tl){
    u32* th16 = (u32*)(sm + SC + 4096);       // raw bf16x2 [256]
    float* lgp = (float*)(sm + SC + 5120);    // [4][64]
    float* lgh = (float*)(sm + SC + 6144);    // [64]
    const u16* tb = tnhb + (size_t)(tl&1)*Bv*Hd + (size_t)rowA*Hd;
    th16[tid] = ld32u(tb + 2*tid);
    __syncthreads();
    {
      int v = tid & 63, ksl = tid >> 6;
      int gv = halfA*64 + v;
      const u16* wp = vocw + (size_t)gv*Hd + ksl*128;
      const u16* hp = (const u16*)th16 + ksl*128;
      float acc = 0.f;
      #pragma unroll 4
      for (int j = 0; j < 16; j++){
        s8 wv8 = *(const s8*)(wp + j*8);
        #pragma unroll
        for (int q = 0; q < 8; q++) acc += bf2f((u16)wv8[q]) * bf2f(hp[j*8+q]);
      }
      lgp[ksl*64 + v] = acc;
    }
    __syncthreads();
    if (tid < 64){
      int gv = halfA*64 + tid;
      float lv = lgp[tid] + lgp[64+tid] + lgp[128+tid] + lgp[192+tid] + p.vocb[gv];
      lgh[tid] = lv;
      float m = wredmax(lv);
      float s = wredsum(expf(lv - m));
      if (tid == 0){
        int tgt = p.E[rowA*Le + tl + 1];
        float tlg = (tgt >= halfA*64 && tgt < halfA*64+64) ? lgh[tgt - halfA*64] : 0.f;
        float* rp = rec + ((size_t)(tl&1)*256 + rowA*2 + halfA)*4;
        union { u64 q; float f[2]; } pk; pk.f[0]=m; pk.f[1]=s;
        st64a(rp, pk.q);
        st32a(rp+2, __float_as_uint(tlg));
      }
    }
    __syncthreads();
  };
  auto COMB = [&](int tl){
    int tgt = p.E[rowA*Le + tl + 1];
    if (tgt != 0){
      const float* rp = rec + ((size_t)(tl&1)*256 + rowA*2)*4;
      union { u64 q; float f[2]; } a, b;
      a.q = ld64a(rp); b.q = ld64a(rp+4);
      float tA = __uint_as_float(ld32u(rp+2)), tB = __uint_as_float(ld32u(rp+6));
      float M = fmaxf(a.f[0], b.f[0]);
      float S = a.f[1]*expf(a.f[0]-M) + b.f[1]*expf(b.f[0]-M);
      accN += logf(S) + M - (tA + tB);
      accC += 1.f;
    }
  };

  // ================= encoder (B-fragments from global wenc) =================
  const int gR0 = (n2*2+0)*512 + cg*16 + (l&15);   // gate rows this thread's B covers
  const int gR1 = (n2*2+1)*512 + cg*16 + (l&15);

  for (int t = 0; t < Lc; t++){
    const u16* hold = hbf + (t&1)*Bv*Hd;           // h_{t-1}
    u16* hnew       = hbf + ((t+1)&1)*Bv*Hd;
    // gather h_{t-1} into LDS slice if it's one of ours
    if (t >= 1 && p.Cpad[rowA*Lc + (t-1)] == 0){
      int idx = (int)pfx[rowA*Lc + (t-1)] - loA;
      if (idx >= 0 && idx < ncapA){
        u32 v = ld32u(hold + (size_t)rowA*Hd + 2*tid);
        *(u32*)((u32*)eL + (size_t)idx*256 + tid) = v;
      }
    }
    s8 a[10];
    #pragma unroll
    for (int ks = 0; ks < 10; ks++){
      int k = k2*320 + ks*32 + kl;
      if (k < 128) a[ks] = cvt8(p.C + ((size_t)ar*Lc + t)*Vc + k);
      else         a[ks] = ld16a(hold + (size_t)ar*Hd + (k-128));
    }
    f4 acc0 = {0,0,0,0}, acc1 = {0,0,0,0};
    #pragma unroll
    for (int ks = 0; ks < 10; ks++){
      int k = k2*320 + ks*32 + kl;
      acc0 = MM(a[ks], *(const s8*)(wenc + (size_t)gR0*KE + k), acc0);
      acc1 = MM(a[ks], *(const s8*)(wenc + (size_t)gR1*KE + k), acc1);
    }
    float* exch = (float*)(sm + SC);
    #pragma unroll
    for (int r = 0; r < 4; r++){
      int row = ((l>>4)<<2) + r;
      exch[((k2*4 + n2*2+0)*16 + row)*16 + (l&15)] = acc0[r];
      exch[((k2*4 + n2*2+1)*16 + row)*16 + (l&15)] = acc1[r];
    }
    __syncthreads();
    {
      int row = tid >> 4, u = tid & 15;
      int gb = cg*16 + u;
      float gi = exch[((0)*16+row)*16+u] + exch[((4)*16+row)*16+u] + be[0*512+gb];
      float gf = exch[((1)*16+row)*16+u] + exch[((5)*16+row)*16+u] + be[1*512+gb];
      float gg = exch[((2)*16+row)*16+u] + exch[((6)*16+row)*16+u] + be[2*512+gb];
      float go = exch[((3)*16+row)*16+u] + exch[((7)*16+row)*16+u] + be[3*512+gb];
      float fi = sigm(gi), ff = sigm(gf), fg = tanhf(gg), fo = sigm(go);
      cst = ff*cst + fi*fg;
      float hn = fo * tanhf(cst);
      int b = rg*16 + row;
      u32 hb = f2bf(hn);
      u32 nb = __shfl_xor((int)hb, 1, 64);
      if ((tid & 1) == 0){
        u32 pk = hb | (nb << 16);
        st32a(hnew + (size_t)b*Hd + gb, pk);
        if (p.Cpad[b*Lc + t] == 0){
          u32 pos = pfx[b*Lc + t];
          st32a(encc + ((size_t)b*Lc + pos)*Hd + gb, pk);
        }
      }
    }
    RGB();
  }
  // final gather: h_{Lc-1} lives in hbf[Lc&1]
  {
    const u16* hlast = hbf + (Lc&1)*Bv*Hd;
    if (p.Cpad[rowA*Lc + (Lc-1)] == 0){
      int idx = (int)pfx[rowA*Lc + (Lc-1)] - loA;
      if (idx >= 0 && idx < ncapA){
        u32 v = ld32u(hlast + (size_t)rowA*Hd + 2*tid);
        *(u32*)((u32*)eL + (size_t)idx*256 + tid) = v;
      }
    }
  }

  GBall();   // flush+inv once: decoder reads encc(overflow)/wdf/etc CACHED

  // ================= decoder =================
  float* exch = (float*)(sm + SC);            // [8][16][16] f32 (8 KB)
  float* vex  = (float*)(sm + SC + 8192);     // [4][16][16] f32 (4 KB)
  float* sc2  = (float*)(sm + SC + 12288);    // [16][2] f32

  for (int t = 0; t < Le-1; t++){
    const u16* hold = hbf + (t&1)*Bv*Hd;
    u16* hnew       = hbf + ((t+1)&1)*Bv*Hd;

    // ======== P1: gates (+ lagged Vnew_{t-1}); B from global ========
    if (t == 0){
      s8 a[10];
      #pragma unroll
      for (int ks = 0; ks < 10; ks++){
        int ke = (k2==0) ? ((ks<4) ? ks*32+kl : 640 + (ks-4)*32 + kl)
                         : (832 + ks*32 + kl);
        if (ke < 128) a[ks] = cvt8(p.Eemb + ((size_t)ar*Le + 0)*Vc + ke);
        else          a[ks] = ld16a(hold + (size_t)ar*Hd + (ke-640));
      }
      f4 acc0 = {0,0,0,0}, acc1 = {0,0,0,0};
      #pragma unroll
      for (int ks = 0; ks < 10; ks++){
        int ke = (k2==0) ? ((ks<4) ? ks*32+kl : 640 + (ks-4)*32 + kl)
                         : (832 + ks*32 + kl);
        acc0 = MM(a[ks], *(const s8*)(wdec + (size_t)gR0*KD + ke), acc0);
        acc1 = MM(a[ks], *(const s8*)(wdec + (size_t)gR1*KD + ke), acc1);
      }
      #pragma unroll
      for (int r = 0; r < 4; r++){
        int row = ((l>>4)<<2) + r;
        exch[((k2*4 + n2*2+0)*16 + row)*16 + (l&15)] = acc0[r];
        exch[((k2*4 + n2*2+1)*16 + row)*16 + (l&15)] = acc1[r];
      }
      __syncthreads();
      {
        int row = tid >> 4, u = tid & 15;
        int gb = cg*16 + u;
        float gi = exch[((0)*16+row)*16+u] + exch[((4)*16+row)*16+u] + bd[0*512+gb];
        float gf = exch[((1)*16+row)*16+u] + exch[((5)*16+row)*16+u] + bd[1*512+gb];
        float gg = exch[((2)*16+row)*16+u] + exch[((6)*16+row)*16+u] + bd[2*512+gb];
        float go = exch[((3)*16+row)*16+u] + exch[((7)*16+row)*16+u] + bd[3*512+gb];
        float fi = sigm(gi), ff = sigm(gf), fg = tanhf(gg), fo = sigm(go);
        cst = ff*cst + fi*fg;
        float hn = fo * tanhf(cst);
        u32 hb = f2bf(hn);
        u32 nb = __shfl_xor((int)hb, 1, 64);
        if ((tid & 1) == 0)
          st32a(hnew + (size_t)(rg*16+row)*Hd + gb, hb | (nb << 16));
      }
    } else {
      if (tid < 16){
        union { u64 q; float f[2]; } uA, uB;
        uA.q = ld64a(pms + (rg*16+tid)*2 + 0);
        uB.q = ld64a(pms + (rg*16+tid)*2 + 1);
        float M = fmaxf(uA.f[0], uB.f[0]);
        float eA = (uA.f[0] > -1e29f) ? expf(uA.f[0]-M) : 0.f;
        float eB = (uB.f[0] > -1e29f) ? expf(uB.f[0]-M) : 0.f;
        float den = uA.f[1]*eA + uB.f[1]*eB;
        sc2[tid*2]   = eA/den;
        sc2[tid*2+1] = eB/den;
      }
      __syncthreads();
      const float scA = sc2[(l&15)*2], scB = sc2[(l&15)*2+1];
      const u16* pA = pacc16 + (size_t)(ar*2+0)*Hd;
      const u16* pB = pacc16 + (size_t)(ar*2+1)*Hd;
      s8 a[18];
      #pragma unroll
      for (int ks = 0; ks < 18; ks++){
        int k = k2*576 + ks*32 + kl;
        if (k < 128)      a[ks] = cvt8(p.Eemb + ((size_t)ar*Le + t)*Vc + k);
        else if (k < 640) a[ks] = ld16a(hold + (size_t)ar*Hd + (k-128));
        else {
          s8 va = ld16a(pA + (k-640));
          s8 vb = ld16a(pB + (k-640));
          s8 r;
          #pragma unroll
          for (int j = 0; j < 8; j++)
            r[j] = (short)f2bf(scA*bf2f((u16)va[j]) + scB*bf2f((u16)vb[j]));
          a[ks] = r;
        }
      }
      f4 acc0 = {0,0,0,0}, acc1 = {0,0,0,0};
      #pragma unroll
      for (int ks = 0; ks < 18; ks++){
        int k = k2*576 + ks*32 + kl;
        acc0 = MM(a[ks], *(const s8*)(wdf + (size_t)gR0*KD + k), acc0);
        acc1 = MM(a[ks], *(const s8*)(wdf + (size_t)gR1*KD + k), acc1);
      }
      // lagged Vnew_{t-1}: A-fragments (k>=128) are exactly U_{t-1}=[h,attn]
      f4 vac = {0,0,0,0};
      const int colc = cg*16 + (l&15);
      #pragma unroll
      for (int ks = 0; ks < 18; ks++){
        int ck = k2*18 + ks - 4;
        if (ck >= 0 && ((ck & 1) == n2))
          vac = MM(a[ks], *(const s8*)(outw + (size_t)colc*1024 + ck*32 + kl), vac);
      }
      #pragma unroll
      for (int r = 0; r < 4; r++){
        int row = ((l>>4)<<2) + r;
        exch[((k2*4 + n2*2+0)*16 + row)*16 + (l&15)] = acc0[r];
        exch[((k2*4 + n2*2+1)*16 + row)*16 + (l&15)] = acc1[r];
        vex[wv*256 + row*16 + (l&15)] = vac[r];
      }
      __syncthreads();
      {
        int row = tid >> 4, u = tid & 15;
        int gb = cg*16 + u;
        float gi = exch[((0)*16+row)*16+u] + exch[((4)*16+row)*16+u] + bdf[0*512+gb];
        float gf = exch[((1)*16+row)*16+u] + exch[((5)*16+row)*16+u] + bdf[1*512+gb];
        float gg = exch[((2)*16+row)*16+u] + exch[((6)*16+row)*16+u] + bdf[2*512+gb];
        float go = exch[((3)*16+row)*16+u] + exch[((7)*16+row)*16+u] + bdf[3*512+gb];
        float fi = sigm(gi), ff = sigm(gf), fg = tanhf(gg), fo = sigm(go);
        cst = ff*cst + fi*fg;
        float hn = fo * tanhf(cst);
        u32 hb = f2bf(hn);
        u32 nb = __shfl_xor((int)hb, 1, 64);
        if ((tid & 1) == 0)
          st32a(hnew + (size_t)(rg*16+row)*Hd + gb, hb | (nb << 16));
        float v = vex[row*16+u] + vex[256+row*16+u] + vex[512+row*16+u]
                + vex[768+row*16+u] + p.outb[gb];
        u32 tb2 = f2bf(tanhf(v));
        u32 tn2 = __shfl_xor((int)tb2, 1, 64);
        if ((tid & 1) == 0){
          u16* tnw = tnhb + (size_t)((t-1)&1)*Bv*Hd;
          st32a(tnw + (size_t)(rg*16+row)*Hd + gb, tb2 | (tn2 << 16));
        }
      }
    }
    RGB();

    // ======== P2: col-split q (16 cols/WG) + lagged CE ========
    {
      s8 ha[4];
      #pragma unroll
      for (int j = 0; j < 4; j++){
        int k = (wv*4 + j)*32 + kl;
        ha[j] = ld16a(hnew + (size_t)(rg*16 + (l&15))*Hd + k);
      }
      f4 acc = {0,0,0,0};
      #pragma unroll
      for (int j = 0; j < 4; j++){
        int k = (wv*4 + j)*32 + kl;
        acc = MM(ha[j], *(const s8*)(attw + (size_t)(cg*16 + (l&15))*Hd + k), acc);
      }
      float* exch4 = (float*)(sm + SC);
      #pragma unroll
      for (int r = 0; r < 4; r++)
        exch4[wv*256 + (((l>>4)<<2)+r)*16 + (l&15)] = acc[r];
      __syncthreads();
      {
        int row = tid >> 4, col = tid & 15;
        float q = exch4[row*16+col] + exch4[256+row*16+col]
                + exch4[512+row*16+col] + exch4[768+row*16+col];
        float qn = __shfl_xor(q, 1, 64);
        if ((tid & 1) == 0){
          union { u64 u; float f[2]; } pk; pk.f[0]=q; pk.f[1]=qn;
          st64a(qg + (size_t)(rg*16+row)*Hd + cg*16 + col, pk.u);
        }
      }
      if (t >= 1) CEREC(t-1);
      if (t >= 2 && halfA == 0 && tid == 0) COMB(t-2);
    }
    RGB();

    // ======== P3: two-pass flash attention from LDS enc_hs ========
    {
      const int n = mynA, ncap = ncapA, st = loA;
      float* qld = (float*)(sm + SC);             // 2 KB permuted q
      float* scl = (float*)(sm + SC + 2048);      // up to 256 f32
      float* red = (float*)(sm + SC + 3104);      // 4 f32
      float* part= (float*)(sm + SC + 3584);      // [4][512] f32, 8 KB
      {
        union { u64 q; float f[2]; } u;
        u.q = ld64a(qg + (size_t)rowA*Hd + 2*tid);
        int c0 = 2*tid, c1 = c0+1;
        qld[(c0&15)*32 + (c0>>4)] = u.f[0];
        qld[(c1&15)*32 + (c1>>4)] = u.f[1];
      }
      __syncthreads();
      const int pg8 = tid >> 5, ln = tid & 31;
      const u16* egl = encc + ((size_t)rowA*Lc + st)*Hd;
      int i = pg8;
      for (; i < ncap; i += 8){
        const u16* e = eL + (size_t)i*Hd + ln*16;
        s8 ev0 = *(const s8*)(e);
        s8 ev1 = *(const s8*)(e+8);
        float s = 0.f;
        #pragma unroll
        for (int j=0;j<8;j++) s += bf2f((u16)ev0[j]) * qld[j*32+ln];
        #pragma unroll
        for (int j=0;j<8;j++) s += bf2f((u16)ev1[j]) * qld[(j+8)*32+ln];
        #pragma unroll
        for (int m=1;m<32;m<<=1) s += __shfl_xor(s, m, 64);
        if (ln == 0) scl[i] = s;
      }
      for (; i < n; i += 8){
        const u16* e = egl + (size_t)i*Hd + ln*16;
        s8 ev0 = *(const s8*)(e);
        s8 ev1 = *(const s8*)(e+8);
        float s = 0.f;
        #pragma unroll
        for (int j=0;j<8;j++) s += bf2f((u16)ev0[j]) * qld[j*32+ln];
        #pragma unroll
        for (int j=0;j<8;j++) s += bf2f((u16)ev1[j]) * qld[(j+8)*32+ln];
        #pragma unroll
        for (int m=1;m<32;m<<=1) s += __shfl_xor(s, m, 64);
        if (ln == 0) scl[i] = s;
      }
      __syncthreads();
      float mloc = -1e30f;
      for (int i2 = tid; i2 < n; i2 += NT) mloc = fmaxf(mloc, scl[i2]);
      mloc = wredmax(mloc);
      if ((tid&63)==0) red[tid>>6] = mloc;
      __syncthreads();
      float M = fmaxf(fmaxf(red[0],red[1]), fmaxf(red[2],red[3]));
      __syncthreads();
      float sloc = 0.f;
      for (int i2 = tid; i2 < n; i2 += NT){ float w = expf(scl[i2]-M); scl[i2]=w; sloc += w; }
      sloc = wredsum(sloc);
      if ((tid&63)==0) red[tid>>6] = sloc;
      __syncthreads();
      float S = red[0]+red[1]+red[2]+red[3];
      float a8[8] = {0,0,0,0,0,0,0,0};
      int ii = wv;
      for (; ii < ncap; ii += 4){
        s8 e0 = *(const s8*)(eL + (size_t)ii*Hd + l*8);
        float w0 = scl[ii];
        #pragma unroll
        for (int j=0;j<8;j++) a8[j] += w0*bf2f((u16)e0[j]);
      }
      for (; ii < n; ii += 4){
        s8 e0 = *(const s8*)(egl + (size_t)ii*Hd + l*8);
        float w0 = scl[ii];
        #pragma unroll
        for (int j=0;j<8;j++) a8[j] += w0*bf2f((u16)e0[j]);
      }
      { f4 v0 = {a8[0],a8[1],a8[2],a8[3]}, v1 = {a8[4],a8[5],a8[6],a8[7]};
        *(f4*)(part + wv*512 + l*8)     = v0;
        *(f4*)(part + wv*512 + l*8 + 4) = v1; }
      __syncthreads();
      {
        int h0 = 2*tid;
        float a0 = part[h0] + part[512+h0] + part[1024+h0] + part[1536+h0];
        float a1 = part[h0+1] + part[512+h0+1] + part[1024+h0+1] + part[1536+h0+1];
        st32a(pacc16 + (size_t)(rowA*2+halfA)*Hd + h0, (u32)f2bf(a0) | ((u32)f2bf(a1) << 16));
        if (tid == 0){
          union { u64 q; float f[2]; } pk; pk.f[0]=M; pk.f[1]=S;
          st64a(pms + rowA*2 + halfA, pk.q);
        }
      }
    }
    RGB();
  }

  // ================= epilogue =================
  const int TL = Le-2;   // 510
  // E1: Vnew_{510} + tanh (all WGs)
  {
    if (tid < 16){
      union { u64 q; float f[2]; } uA, uB;
      uA.q = ld64a(pms + (rg*16+tid)*2 + 0);
      uB.q = ld64a(pms + (rg*16+tid)*2 + 1);
      float M = fmaxf(uA.f[0], uB.f[0]);
      float eA = (uA.f[0] > -1e29f) ? expf(uA.f[0]-M) : 0.f;
      float eB = (uB.f[0] > -1e29f) ? expf(uB.f[0]-M) : 0.f;
      float den = uA.f[1]*eA + uB.f[1]*eB;
      sc2[tid*2]   = eA/den;
      sc2[tid*2+1] = eB/den;
    }
    __syncthreads();
    const float scA = sc2[(l&15)*2], scB = sc2[(l&15)*2+1];
    const u16* h5 = hbf + (size_t)((TL+1)&1)*Bv*Hd;
    const u16* pA = pacc16 + (size_t)(ar*2+0)*Hd;
    const u16* pB = pacc16 + (size_t)(ar*2+1)*Hd;
    const int colc = cg*16 + (l&15);
    f4 vac = {0,0,0,0};
    #pragma unroll
    for (int j = 0; j < 8; j++){
      int kv = k2*16 + j*2 + n2;
      s8 af;
      if (kv < 16) af = ld16a(h5 + (size_t)ar*Hd + kv*32 + kl);
      else {
        s8 va = ld16a(pA + (kv-16)*32 + kl);
        s8 vb = ld16a(pB + (kv-16)*32 + kl);
        #pragma unroll
        for (int q = 0; q < 8; q++)
          af[q] = (short)f2bf(scA*bf2f((u16)va[q]) + scB*bf2f((u16)vb[q]));
      }
      vac = MM(af, *(const s8*)(outw + (size_t)colc*1024 + kv*32 + kl), vac);
    }
    #pragma unroll
    for (int r = 0; r < 4; r++)
      vex[wv*256 + (((l>>4)<<2)+r)*16 + (l&15)] = vac[r];
    __syncthreads();
    {
      int row = tid >> 4, u = tid & 15;
      int gb = cg*16 + u;
      float v = vex[row*16+u] + vex[256+row*16+u] + vex[512+row*16+u]
              + vex[768+row*16+u] + p.outb[gb];
      u32 tb2 = f2bf(tanhf(v));
      u32 tn2 = __shfl_xor((int)tb2, 1, 64);
      if ((tid & 1) == 0){
        u16* tnw = tnhb + (size_t)(TL&1)*Bv*Hd;
        st32a(tnw + (size_t)(rg*16+row)*Hd + gb, tb2 | (tn2 << 16));
      }
    }
  }
  RGB();
  // E2: CE record for step 510 + combine 509
  {
    CEREC(TL);
    if (halfA == 0 && tid == 0) COMB(TL-1);
  }
  RGB();
  // E3: combine step 510, then accumulate loss
  {
    if (halfA == 0 && tid == 0){
      COMB(TL);
      atomicAdd(losp + 0, accN);
      atomicAdd(losp + 1, accC);
    }
  }
  GBall();
  if (wg == 0 && tid == 0) p.out[0] = losp[0] / fmaxf(losp[1], 1.f);
}

extern "C" void kernel_launch(void* const* d_in, const int* in_sizes, int n_in,
                              void* d_out, int out_size, void* d_ws, size_t ws_size,
                              hipStream_t stream)
{
  hipFuncSetAttribute(reinterpret_cast<const void*>(k_main),
                      hipFuncAttributeMaxDynamicSharedMemorySize, SM_BYTES);
  hipMemsetAsync(d_ws, 0, 4096, stream);

  P prm;
  prm.C    = (const float*)d_in[0];
  prm.Cpad = (const int*)  d_in[1];
  prm.E    = (const int*)  d_in[2];
  prm.Eemb = (const float*)d_in[3];
  prm.eWih = (const float*)d_in[4];
  prm.eWhh = (const float*)d_in[5];
  prm.ebih = (const float*)d_in[6];
  prm.ebhh = (const float*)d_in[7];
  prm.dWih = (const float*)d_in[8];
  prm.dWhh = (const float*)d_in[9];
  prm.dbih = (const float*)d_in[10];
  prm.dbhh = (const float*)d_in[11];
  prm.attW = (const float*)d_in[12];
  prm.outW = (const float*)d_in[13];
  prm.outb = (const float*)d_in[14];
  prm.vocW = (const float*)d_in[15];
  prm.vocb = (const float*)d_in[16];
  prm.ws   = (char*)d_ws;
  prm.out  = (float*)d_out;

  k_main<<<dim3(NWG), dim3(NT), SM_BYTES, stream>>>(prm);
}

// Round 7
// 21101.488 us; speedup vs baseline: 1.6932x; 1.0779x over previous
//
#include <hip/hip_runtime.h>
#include <hip/hip_bf16.h>

// Persistent-kernel seq2seq (enc LSTM -> attn decoder -> CE loss) for MI355X.
// R7: ownership remap rg=wg>>5, cg=wg&31 so the 8 WGs sharing a weight slice
// (same cg) are co-resident on ONE XCD (wg = cg mod 8 is XCD-stable heuristic)
// -> per-XCD weight working set ~0.9MB, L2-resident across all steps.
// Otherwise identical to R6: enc_hs in LDS, folded gates, 3 phases/step.

#define NWG 256
#define NT  256

typedef unsigned short u16;
typedef unsigned int   u32;
typedef unsigned long long u64;
typedef __attribute__((ext_vector_type(4))) float f4;
typedef __attribute__((ext_vector_type(8))) short s8;

constexpr int Bv=128, Lc=512, Le=512, Hd=512, Vc=128;
constexpr int KE=640, KD=1152;
constexpr int CAP = 144;                       // LDS-resident positions per WG

// ---- workspace layout (bytes) ----
constexpr size_t O_WENC = 4096;                                // bf16 [2048][640]
constexpr size_t O_WDEC = O_WENC + (size_t)2048*KE*2;          // bf16 [2048][1152] orig (t=0)
constexpr size_t O_WDF  = O_WDEC + (size_t)2048*KD*2;          // bf16 [2048][1152] folded
constexpr size_t O_ATTW = O_WDF  + (size_t)2048*KD*2;          // bf16 [512][512]
constexpr size_t O_OUTW = O_ATTW + (size_t)512*512*2;          // bf16 [512][1024]
constexpr size_t O_VOCW = O_OUTW + (size_t)512*1024*2;         // bf16 [128][512]
constexpr size_t O_BE   = O_VOCW + (size_t)128*512*2;          // f32[2048]
constexpr size_t O_BD   = O_BE + 8192;                         // f32[2048] orig
constexpr size_t O_BDF  = O_BD + 8192;                         // f32[2048] folded
constexpr size_t O_H    = O_BDF + 8192;                        // bf16 [2][128][512]
constexpr size_t O_TNH  = O_H + (size_t)2*128*512*2;           // bf16 [2][128][512]
constexpr size_t O_Q    = O_TNH + (size_t)2*128*512*2;         // f32 [128][512]
constexpr size_t O_PFX  = O_Q + (size_t)128*512*4;             // u32 [128][512]
constexpr size_t O_CNT  = O_PFX + (size_t)128*512*4;           // u32[128]
constexpr size_t O_PMS  = O_CNT + 512;                         // u64 [128][2] (m,s)
constexpr size_t O_PACC = O_PMS + 2048;                        // bf16 [128][2][512]
constexpr size_t O_REC  = O_PACC + (size_t)256*512*2;          // f32 [2][128][2][4]
constexpr size_t O_LOSS = O_REC + (size_t)2*128*2*4*4;         // f32[2]
constexpr size_t O_ENC  = O_LOSS + 256;                        // bf16 [128][512][512]

// ---- LDS: [0, CAP*1024) = enc_hs slice; [SC, SC+16K) = phase scratch ----
constexpr int SC       = CAP*1024;             // 147456
constexpr int SM_BYTES = SC + 16384;           // 163840 (160 KB)

struct P {
  const float *C; const int *Cpad; const int *E; const float *Eemb;
  const float *eWih,*eWhh,*ebih,*ebhh;
  const float *dWih,*dWhh,*dbih,*dbhh;
  const float *attW,*outW,*outb,*vocW,*vocb;
  char* ws; float* out;
};

__device__ inline u16 f2bf(float x){
  u32 u = __float_as_uint(x);
  return (u16)((u + 0x7fffu + ((u>>16)&1u)) >> 16);
}
__device__ inline float bf2f(u16 b){ return __uint_as_float(((u32)b)<<16); }
__device__ inline float sigm(float x){ return 1.f/(1.f+expf(-x)); }
__device__ inline f4 MM(s8 a, s8 b, f4 c){
  return __builtin_amdgcn_mfma_f32_16x16x32_bf16(a, b, c, 0, 0, 0);
}
// device-scope relaxed (cache-bypass) helpers
__device__ inline u64 ld64a(const void* p){
  return __hip_atomic_load((const u64*)p, __ATOMIC_RELAXED, __HIP_MEMORY_SCOPE_AGENT);
}
__device__ inline u32 ld32u(const void* p){
  return __hip_atomic_load((const u32*)p, __ATOMIC_RELAXED, __HIP_MEMORY_SCOPE_AGENT);
}
__device__ inline void st64a(void* p, u64 v){
  __hip_atomic_store((u64*)p, v, __ATOMIC_RELAXED, __HIP_MEMORY_SCOPE_AGENT);
}
__device__ inline void st32a(void* p, u32 v){
  __hip_atomic_store((u32*)p, v, __ATOMIC_RELAXED, __HIP_MEMORY_SCOPE_AGENT);
}
__device__ inline s8 ld16a(const void* p){
  union { u64 q[2]; s8 v; } u;
  u.q[0] = ld64a(p); u.q[1] = ld64a((const char*)p + 8);
  return u.v;
}
__device__ inline s8 cvt8(const float* p){
  f4 u = *(const f4*)p, v = *(const f4*)(p+4);
  s8 r;
  r[0]=(short)f2bf(u[0]); r[1]=(short)f2bf(u[1]); r[2]=(short)f2bf(u[2]); r[3]=(short)f2bf(u[3]);
  r[4]=(short)f2bf(v[0]); r[5]=(short)f2bf(v[1]); r[6]=(short)f2bf(v[2]); r[7]=(short)f2bf(v[3]);
  return r;
}
__device__ inline float wredmax(float v){
  #pragma unroll
  for (int m=32;m;m>>=1) v = fmaxf(v, __shfl_xor(v,m,64));
  return v;
}
__device__ inline float wredsum(float v){
  #pragma unroll
  for (int m=32;m;m>>=1) v += __shfl_xor(v,m,64);
  return v;
}

extern "C" __global__ void __launch_bounds__(NT,1) k_main(P p)
{
  extern __shared__ char sm[];
  const int wg = blockIdx.x, tid = threadIdx.x;
  const int gt = wg*NT + tid;
  // R7 mapping: weight-sharing set (same cg) = {cg, cg+32, ...} -> all on one
  // XCD (wg mod 8 = cg mod 8). Rowgroup rg spans XCDs; its traffic is small.
  const int rg = wg >> 5, cg = wg & 31;

  char* ws = p.ws;
  u32*  barAll  = (u32*)ws;
  u32*  flagAll = (u32*)(ws + 128);
  u32*  barRG   = (u32*)(ws + 512 + rg*256);
  u32*  flagRG  = (u32*)(ws + 512 + rg*256 + 128);
  u16*  wenc = (u16*)(ws + O_WENC);
  u16*  wdec = (u16*)(ws + O_WDEC);
  u16*  wdf  = (u16*)(ws + O_WDF);
  u16*  attw = (u16*)(ws + O_ATTW);
  u16*  outw = (u16*)(ws + O_OUTW);
  u16*  vocw = (u16*)(ws + O_VOCW);
  float* be  = (float*)(ws + O_BE);
  float* bd  = (float*)(ws + O_BD);
  float* bdf = (float*)(ws + O_BDF);
  u16*  hbf  = (u16*)(ws + O_H);
  u16*  tnhb = (u16*)(ws + O_TNH);
  float* qg  = (float*)(ws + O_Q);
  u32*  pfx  = (u32*)(ws + O_PFX);
  u32*  cntp = (u32*)(ws + O_CNT);
  u64*  pms  = (u64*)(ws + O_PMS);
  u16*  pacc16 = (u16*)(ws + O_PACC);
  float* rec = (float*)(ws + O_REC);
  float* losp= (float*)(ws + O_LOSS);
  u16*  encc = (u16*)(ws + O_ENC);

  u32 genA = 0, genG = 0;
  auto GBall = [&](){
    genA++;
    __syncthreads();
    if (tid == 0){
      __builtin_amdgcn_fence(__ATOMIC_RELEASE, "agent");
      u32 old = __hip_atomic_fetch_add(barAll, 1u, __ATOMIC_RELAXED, __HIP_MEMORY_SCOPE_AGENT);
      if (old == genA*(u32)NWG - 1u) st32a(flagAll, genA);
      else while (ld32u(flagAll) < genA) __builtin_amdgcn_s_sleep(2);
      __builtin_amdgcn_fence(__ATOMIC_ACQUIRE, "agent");
    }
    __syncthreads();
  };
  auto RGB = [&](){
    genG++;
    __syncthreads();
    if (tid == 0){
      u32 old = __hip_atomic_fetch_add(barRG, 1u, __ATOMIC_RELAXED, __HIP_MEMORY_SCOPE_AGENT);
      if (old == genG*32u - 1u) st32a(flagRG, genG);
      else while (ld32u(flagRG) < genG) __builtin_amdgcn_s_sleep(1);
      __builtin_amdgcn_fence(__ATOMIC_ACQUIRE, "workgroup");
    }
    __syncthreads();
  };

  // ================= phase 0: convert, fold, init =================
  for (int i = gt; i < 2048*KE; i += NWG*NT){
    int row = i / KE, k = i - row*KE;
    float v = (k < 128) ? p.eWih[row*128 + k] : p.eWhh[row*512 + (k-128)];
    wenc[i] = f2bf(v);
  }
  for (int i = gt; i < 2048*KD; i += NWG*NT){
    int row = i / KD, k = i - row*KD;
    float v = (k < 640) ? p.dWih[row*640 + k] : p.dWhh[row*512 + (k-640)];
    wdec[i] = f2bf(v);
  }
  for (int i = gt; i < 512*512;  i += NWG*NT) attw[i] = f2bf(p.attW[i]);
  for (int i = gt; i < 512*1024; i += NWG*NT) outw[i] = f2bf(p.outW[i]);
  for (int i = gt; i < 128*512;  i += NWG*NT) vocw[i] = f2bf(p.vocW[i]);
  for (int i = gt; i < 2048;     i += NWG*NT){ be[i] = p.ebih[i]+p.ebhh[i]; bd[i] = p.dbih[i]+p.dbhh[i]; }
  { u32* hz = (u32*)hbf; for (int i = gt; i < 65536; i += NWG*NT) hz[i] = 0; }
  if (gt == 0){ losp[0] = 0.f; losp[1] = 0.f; }

  // --- W2 = dWv @ outW fold; wdf/bdf build. WG owns 8 gate-rows. ---
  {
    const int g0 = wg*8;
    float* dv = (float*)sm;                      // [8][512] f32 (enc_hs region, pre-encoder)
    for (int i = tid; i < 8*512; i += NT)
      dv[i] = p.dWih[(size_t)(g0 + (i>>9))*640 + 128 + (i&511)];
    __syncthreads();
    float wa[8][4];
    #pragma unroll
    for (int r=0;r<8;r++){ wa[r][0]=0;wa[r][1]=0;wa[r][2]=0;wa[r][3]=0; }
    for (int o = 0; o < 512; o++){
      float b0 = p.outW[(size_t)o*1024 + tid];
      float b1 = p.outW[(size_t)o*1024 + 256 + tid];
      float b2 = p.outW[(size_t)o*1024 + 512 + tid];
      float b3 = p.outW[(size_t)o*1024 + 768 + tid];
      #pragma unroll
      for (int r=0;r<8;r++){
        float d = dv[r*512+o];
        wa[r][0] += d*b0; wa[r][1] += d*b1; wa[r][2] += d*b2; wa[r][3] += d*b3;
      }
    }
    #pragma unroll
    for (int r=0;r<8;r++){
      int g = g0 + r;
      #pragma unroll
      for (int j=0;j<4;j++){
        int c = tid + 256*j;
        if (c < 512) wdf[(size_t)g*KD + 128 + c] = f2bf(p.dWhh[(size_t)g*512 + c] + wa[r][j]);
        else         wdf[(size_t)g*KD + 640 + (c-512)] = f2bf(wa[r][j]);
      }
    }
    for (int i = tid; i < 8*128; i += NT){
      int r = i >> 7, k = i & 127;
      wdf[(size_t)(g0+r)*KD + k] = f2bf(p.dWih[(size_t)(g0+r)*640 + k]);
    }
    if (tid < 8){
      int g = g0 + tid;
      float s = p.dbih[g] + p.dbhh[g];
      for (int o = 0; o < 512; o++) s += dv[tid*512+o]*p.outb[o];
      bdf[g] = s;
    }
    __syncthreads();
  }

  if (wg < 128){
    int* padl = (int*)(sm + SC);
    for (int i = tid; i < 512; i += NT) padl[i] = p.Cpad[wg*512 + i];
    __syncthreads();
    if (tid == 0){
      u32 run = 0;
      for (int tt = 0; tt < 512; tt++){ pfx[wg*512+tt] = run; if (padl[tt] == 0) run++; }
      cntp[wg] = run;
    }
    __syncthreads();
  }
  GBall();

  const int l  = tid & 63, wv = tid >> 6;
  const int n2 = wv >> 1, k2 = wv & 1;
  const int kl = (l>>4) << 3;
  const int ar = rg*16 + (l&15);
  float cst = 0.f;
  float accN = 0.f, accC = 0.f;

  // attention ownership: 2 WGs per batch row
  const int rowA = rg*16 + (cg >> 1), halfA = cg & 1;
  const int cnA = (int)cntp[rowA], c2A = cnA >> 1;
  const int loA = halfA ? c2A : 0;
  const int mynA = (halfA ? cnA : c2A) - loA;
  const int ncapA = mynA < CAP ? mynA : CAP;
  u16* eL = (u16*)sm;   // LDS enc_hs slice [CAP][512] bf16

  // CE record for step tl (this WG's vocab half of its row)
  auto CEREC = [&](int tl){
    u32* th16 = (u32*)(sm + SC + 4096);       // raw bf16x2 [256]
    float* lgp = (float*)(sm + SC + 5120);    // [4][64]
    float* lgh = (float*)(sm + SC + 6144);    // [64]
    const u16* tb = tnhb + (size_t)(tl&1)*Bv*Hd + (size_t)rowA*Hd;
    th16[tid] = ld32u(tb + 2*tid);
    __syncthreads();
    {
      int v = tid & 63, ksl = tid >> 6;
      int gv = halfA*64 + v;
      const u16* wp = vocw + (size_t)gv*Hd + ksl*128;
      const u16* hp = (const u16*)th16 + ksl*128;
      float acc = 0.f;
      #pragma unroll 4
      for (int j = 0; j < 16; j++){
        s8 wv8 = *(const s8*)(wp + j*8);
        #pragma unroll
        for (int q = 0; q < 8; q++) acc += bf2f((u16)wv8[q]) * bf2f(hp[j*8+q]);
      }
      lgp[ksl*64 + v] = acc;
    }
    __syncthreads();
    if (tid < 64){
      int gv = halfA*64 + tid;
      float lv = lgp[tid] + lgp[64+tid] + lgp[128+tid] + lgp[192+tid] + p.vocb[gv];
      lgh[tid] = lv;
      float m = wredmax(lv);
      float s = wredsum(expf(lv - m));
      if (tid == 0){
        int tgt = p.E[rowA*Le + tl + 1];
        float tlg = (tgt >= halfA*64 && tgt < halfA*64+64) ? lgh[tgt - halfA*64] : 0.f;
        float* rp = rec + ((size_t)(tl&1)*256 + rowA*2 + halfA)*4;
        union { u64 q; float f[2]; } pk; pk.f[0]=m; pk.f[1]=s;
        st64a(rp, pk.q);
        st32a(rp+2, __float_as_uint(tlg));
      }
    }
    __syncthreads();
  };
  auto COMB = [&](int tl){
    int tgt = p.E[rowA*Le + tl + 1];
    if (tgt != 0){
      const float* rp = rec + ((size_t)(tl&1)*256 + rowA*2)*4;
      union { u64 q; float f[2]; } a, b;
      a.q = ld64a(rp); b.q = ld64a(rp+4);
      float tA = __uint_as_float(ld32u(rp+2)), tB = __uint_as_float(ld32u(rp+6));
      float M = fmaxf(a.f[0], b.f[0]);
      float S = a.f[1]*expf(a.f[0]-M) + b.f[1]*expf(b.f[0]-M);
      accN += logf(S) + M - (tA + tB);
      accC += 1.f;
    }
  };

  // ================= encoder (B-fragments from global wenc) =================
  const int gR0 = (n2*2+0)*512 + cg*16 + (l&15);   // gate rows this thread's B covers
  const int gR1 = (n2*2+1)*512 + cg*16 + (l&15);

  for (int t = 0; t < Lc; t++){
    const u16* hold = hbf + (t&1)*Bv*Hd;           // h_{t-1}
    u16* hnew       = hbf + ((t+1)&1)*Bv*Hd;
    // gather h_{t-1} into LDS slice if it's one of ours
    if (t >= 1 && p.Cpad[rowA*Lc + (t-1)] == 0){
      int idx = (int)pfx[rowA*Lc + (t-1)] - loA;
      if (idx >= 0 && idx < ncapA){
        u32 v = ld32u(hold + (size_t)rowA*Hd + 2*tid);
        *(u32*)((u32*)eL + (size_t)idx*256 + tid) = v;
      }
    }
    s8 a[10];
    #pragma unroll
    for (int ks = 0; ks < 10; ks++){
      int k = k2*320 + ks*32 + kl;
      if (k < 128) a[ks] = cvt8(p.C + ((size_t)ar*Lc + t)*Vc + k);
      else         a[ks] = ld16a(hold + (size_t)ar*Hd + (k-128));
    }
    f4 acc0 = {0,0,0,0}, acc1 = {0,0,0,0};
    #pragma unroll
    for (int ks = 0; ks < 10; ks++){
      int k = k2*320 + ks*32 + kl;
      acc0 = MM(a[ks], *(const s8*)(wenc + (size_t)gR0*KE + k), acc0);
      acc1 = MM(a[ks], *(const s8*)(wenc + (size_t)gR1*KE + k), acc1);
    }
    float* exch = (float*)(sm + SC);
    #pragma unroll
    for (int r = 0; r < 4; r++){
      int row = ((l>>4)<<2) + r;
      exch[((k2*4 + n2*2+0)*16 + row)*16 + (l&15)] = acc0[r];
      exch[((k2*4 + n2*2+1)*16 + row)*16 + (l&15)] = acc1[r];
    }
    __syncthreads();
    {
      int row = tid >> 4, u = tid & 15;
      int gb = cg*16 + u;
      float gi = exch[((0)*16+row)*16+u] + exch[((4)*16+row)*16+u] + be[0*512+gb];
      float gf = exch[((1)*16+row)*16+u] + exch[((5)*16+row)*16+u] + be[1*512+gb];
      float gg = exch[((2)*16+row)*16+u] + exch[((6)*16+row)*16+u] + be[2*512+gb];
      float go = exch[((3)*16+row)*16+u] + exch[((7)*16+row)*16+u] + be[3*512+gb];
      float fi = sigm(gi), ff = sigm(gf), fg = tanhf(gg), fo = sigm(go);
      cst = ff*cst + fi*fg;
      float hn = fo * tanhf(cst);
      int b = rg*16 + row;
      u32 hb = f2bf(hn);
      u32 nb = __shfl_xor((int)hb, 1, 64);
      if ((tid & 1) == 0){
        u32 pk = hb | (nb << 16);
        st32a(hnew + (size_t)b*Hd + gb, pk);
        if (p.Cpad[b*Lc + t] == 0){
          u32 pos = pfx[b*Lc + t];
          st32a(encc + ((size_t)b*Lc + pos)*Hd + gb, pk);
        }
      }
    }
    RGB();
  }
  // final gather: h_{Lc-1} lives in hbf[Lc&1]
  {
    const u16* hlast = hbf + (Lc&1)*Bv*Hd;
    if (p.Cpad[rowA*Lc + (Lc-1)] == 0){
      int idx = (int)pfx[rowA*Lc + (Lc-1)] - loA;
      if (idx >= 0 && idx < ncapA){
        u32 v = ld32u(hlast + (size_t)rowA*Hd + 2*tid);
        *(u32*)((u32*)eL + (size_t)idx*256 + tid) = v;
      }
    }
  }

  GBall();   // flush+inv once: decoder reads encc(overflow)/wdf/etc CACHED

  // ================= decoder =================
  float* exch = (float*)(sm + SC);            // [8][16][16] f32 (8 KB)
  float* vex  = (float*)(sm + SC + 8192);     // [4][16][16] f32 (4 KB)
  float* sc2  = (float*)(sm + SC + 12288);    // [16][2] f32

  for (int t = 0; t < Le-1; t++){
    const u16* hold = hbf + (t&1)*Bv*Hd;
    u16* hnew       = hbf + ((t+1)&1)*Bv*Hd;

    // ======== P1: gates (+ lagged Vnew_{t-1}); B from global ========
    if (t == 0){
      s8 a[10];
      #pragma unroll
      for (int ks = 0; ks < 10; ks++){
        int ke = (k2==0) ? ((ks<4) ? ks*32+kl : 640 + (ks-4)*32 + kl)
                         : (832 + ks*32 + kl);
        if (ke < 128) a[ks] = cvt8(p.Eemb + ((size_t)ar*Le + 0)*Vc + ke);
        else          a[ks] = ld16a(hold + (size_t)ar*Hd + (ke-640));
      }
      f4 acc0 = {0,0,0,0}, acc1 = {0,0,0,0};
      #pragma unroll
      for (int ks = 0; ks < 10; ks++){
        int ke = (k2==0) ? ((ks<4) ? ks*32+kl : 640 + (ks-4)*32 + kl)
                         : (832 + ks*32 + kl);
        acc0 = MM(a[ks], *(const s8*)(wdec + (size_t)gR0*KD + ke), acc0);
        acc1 = MM(a[ks], *(const s8*)(wdec + (size_t)gR1*KD + ke), acc1);
      }
      #pragma unroll
      for (int r = 0; r < 4; r++){
        int row = ((l>>4)<<2) + r;
        exch[((k2*4 + n2*2+0)*16 + row)*16 + (l&15)] = acc0[r];
        exch[((k2*4 + n2*2+1)*16 + row)*16 + (l&15)] = acc1[r];
      }
      __syncthreads();
      {
        int row = tid >> 4, u = tid & 15;
        int gb = cg*16 + u;
        float gi = exch[((0)*16+row)*16+u] + exch[((4)*16+row)*16+u] + bd[0*512+gb];
        float gf = exch[((1)*16+row)*16+u] + exch[((5)*16+row)*16+u] + bd[1*512+gb];
        float gg = exch[((2)*16+row)*16+u] + exch[((6)*16+row)*16+u] + bd[2*512+gb];
        float go = exch[((3)*16+row)*16+u] + exch[((7)*16+row)*16+u] + bd[3*512+gb];
        float fi = sigm(gi), ff = sigm(gf), fg = tanhf(gg), fo = sigm(go);
        cst = ff*cst + fi*fg;
        float hn = fo * tanhf(cst);
        u32 hb = f2bf(hn);
        u32 nb = __shfl_xor((int)hb, 1, 64);
        if ((tid & 1) == 0)
          st32a(hnew + (size_t)(rg*16+row)*Hd + gb, hb | (nb << 16));
      }
    } else {
      if (tid < 16){
        union { u64 q; float f[2]; } uA, uB;
        uA.q = ld64a(pms + (rg*16+tid)*2 + 0);
        uB.q = ld64a(pms + (rg*16+tid)*2 + 1);
        float M = fmaxf(uA.f[0], uB.f[0]);
        float eA = (uA.f[0] > -1e29f) ? expf(uA.f[0]-M) : 0.f;
        float eB = (uB.f[0] > -1e29f) ? expf(uB.f[0]-M) : 0.f;
        float den = uA.f[1]*eA + uB.f[1]*eB;
        sc2[tid*2]   = eA/den;
        sc2[tid*2+1] = eB/den;
      }
      __syncthreads();
      const float scA = sc2[(l&15)*2], scB = sc2[(l&15)*2+1];
      const u16* pA = pacc16 + (size_t)(ar*2+0)*Hd;
      const u16* pB = pacc16 + (size_t)(ar*2+1)*Hd;
      s8 a[18];
      #pragma unroll
      for (int ks = 0; ks < 18; ks++){
        int k = k2*576 + ks*32 + kl;
        if (k < 128)      a[ks] = cvt8(p.Eemb + ((size_t)ar*Le + t)*Vc + k);
        else if (k < 640) a[ks] = ld16a(hold + (size_t)ar*Hd + (k-128));
        else {
          s8 va = ld16a(pA + (k-640));
          s8 vb = ld16a(pB + (k-640));
          s8 r;
          #pragma unroll
          for (int j = 0; j < 8; j++)
            r[j] = (short)f2bf(scA*bf2f((u16)va[j]) + scB*bf2f((u16)vb[j]));
          a[ks] = r;
        }
      }
      f4 acc0 = {0,0,0,0}, acc1 = {0,0,0,0};
      #pragma unroll
      for (int ks = 0; ks < 18; ks++){
        int k = k2*576 + ks*32 + kl;
        acc0 = MM(a[ks], *(const s8*)(wdf + (size_t)gR0*KD + k), acc0);
        acc1 = MM(a[ks], *(const s8*)(wdf + (size_t)gR1*KD + k), acc1);
      }
      // lagged Vnew_{t-1}: A-fragments (k>=128) are exactly U_{t-1}=[h,attn]
      f4 vac = {0,0,0,0};
      const int colc = cg*16 + (l&15);
      #pragma unroll
      for (int ks = 0; ks < 18; ks++){
        int ck = k2*18 + ks - 4;
        if (ck >= 0 && ((ck & 1) == n2))
          vac = MM(a[ks], *(const s8*)(outw + (size_t)colc*1024 + ck*32 + kl), vac);
      }
      #pragma unroll
      for (int r = 0; r < 4; r++){
        int row = ((l>>4)<<2) + r;
        exch[((k2*4 + n2*2+0)*16 + row)*16 + (l&15)] = acc0[r];
        exch[((k2*4 + n2*2+1)*16 + row)*16 + (l&15)] = acc1[r];
        vex[wv*256 + row*16 + (l&15)] = vac[r];
      }
      __syncthreads();
      {
        int row = tid >> 4, u = tid & 15;
        int gb = cg*16 + u;
        float gi = exch[((0)*16+row)*16+u] + exch[((4)*16+row)*16+u] + bdf[0*512+gb];
        float gf = exch[((1)*16+row)*16+u] + exch[((5)*16+row)*16+u] + bdf[1*512+gb];
        float gg = exch[((2)*16+row)*16+u] + exch[((6)*16+row)*16+u] + bdf[2*512+gb];
        float go = exch[((3)*16+row)*16+u] + exch[((7)*16+row)*16+u] + bdf[3*512+gb];
        float fi = sigm(gi), ff = sigm(gf), fg = tanhf(gg), fo = sigm(go);
        cst = ff*cst + fi*fg;
        float hn = fo * tanhf(cst);
        u32 hb = f2bf(hn);
        u32 nb = __shfl_xor((int)hb, 1, 64);
        if ((tid & 1) == 0)
          st32a(hnew + (size_t)(rg*16+row)*Hd + gb, hb | (nb << 16));
        float v = vex[row*16+u] + vex[256+row*16+u] + vex[512+row*16+u]
                + vex[768+row*16+u] + p.outb[gb];
        u32 tb2 = f2bf(tanhf(v));
        u32 tn2 = __shfl_xor((int)tb2, 1, 64);
        if ((tid & 1) == 0){
          u16* tnw = tnhb + (size_t)((t-1)&1)*Bv*Hd;
          st32a(tnw + (size_t)(rg*16+row)*Hd + gb, tb2 | (tn2 << 16));
        }
      }
    }
    RGB();

    // ======== P2: col-split q (16 cols/WG) + lagged CE ========
    {
      s8 ha[4];
      #pragma unroll
      for (int j = 0; j < 4; j++){
        int k = (wv*4 + j)*32 + kl;
        ha[j] = ld16a(hnew + (size_t)(rg*16 + (l&15))*Hd + k);
      }
      f4 acc = {0,0,0,0};
      #pragma unroll
      for (int j = 0; j < 4; j++){
        int k = (wv*4 + j)*32 + kl;
        acc = MM(ha[j], *(const s8*)(attw + (size_t)(cg*16 + (l&15))*Hd + k), acc);
      }
      float* exch4 = (float*)(sm + SC);
      #pragma unroll
      for (int r = 0; r < 4; r++)
        exch4[wv*256 + (((l>>4)<<2)+r)*16 + (l&15)] = acc[r];
      __syncthreads();
      {
        int row = tid >> 4, col = tid & 15;
        float q = exch4[row*16+col] + exch4[256+row*16+col]
                + exch4[512+row*16+col] + exch4[768+row*16+col];
        float qn = __shfl_xor(q, 1, 64);
        if ((tid & 1) == 0){
          union { u64 u; float f[2]; } pk; pk.f[0]=q; pk.f[1]=qn;
          st64a(qg + (size_t)(rg*16+row)*Hd + cg*16 + col, pk.u);
        }
      }
      if (t >= 1) CEREC(t-1);
      if (t >= 2 && halfA == 0 && tid == 0) COMB(t-2);
    }
    RGB();

    // ======== P3: two-pass flash attention from LDS enc_hs ========
    {
      const int n = mynA, ncap = ncapA, st = loA;
      float* qld = (float*)(sm + SC);             // 2 KB permuted q
      float* scl = (float*)(sm + SC + 2048);      // up to 256 f32
      float* red = (float*)(sm + SC + 3104);      // 4 f32
      float* part= (float*)(sm + SC + 3584);      // [4][512] f32, 8 KB
      {
        union { u64 q; float f[2]; } u;
        u.q = ld64a(qg + (size_t)rowA*Hd + 2*tid);
        int c0 = 2*tid, c1 = c0+1;
        qld[(c0&15)*32 + (c0>>4)] = u.f[0];
        qld[(c1&15)*32 + (c1>>4)] = u.f[1];
      }
      __syncthreads();
      const int pg8 = tid >> 5, ln = tid & 31;
      const u16* egl = encc + ((size_t)rowA*Lc + st)*Hd;
      int i = pg8;
      for (; i < ncap; i += 8){
        const u16* e = eL + (size_t)i*Hd + ln*16;
        s8 ev0 = *(const s8*)(e);
        s8 ev1 = *(const s8*)(e+8);
        float s = 0.f;
        #pragma unroll
        for (int j=0;j<8;j++) s += bf2f((u16)ev0[j]) * qld[j*32+ln];
        #pragma unroll
        for (int j=0;j<8;j++) s += bf2f((u16)ev1[j]) * qld[(j+8)*32+ln];
        #pragma unroll
        for (int m=1;m<32;m<<=1) s += __shfl_xor(s, m, 64);
        if (ln == 0) scl[i] = s;
      }
      for (; i < n; i += 8){
        const u16* e = egl + (size_t)i*Hd + ln*16;
        s8 ev0 = *(const s8*)(e);
        s8 ev1 = *(const s8*)(e+8);
        float s = 0.f;
        #pragma unroll
        for (int j=0;j<8;j++) s += bf2f((u16)ev0[j]) * qld[j*32+ln];
        #pragma unroll
        for (int j=0;j<8;j++) s += bf2f((u16)ev1[j]) * qld[(j+8)*32+ln];
        #pragma unroll
        for (int m=1;m<32;m<<=1) s += __shfl_xor(s, m, 64);
        if (ln == 0) scl[i] = s;
      }
      __syncthreads();
      float mloc = -1e30f;
      for (int i2 = tid; i2 < n; i2 += NT) mloc = fmaxf(mloc, scl[i2]);
      mloc = wredmax(mloc);
      if ((tid&63)==0) red[tid>>6] = mloc;
      __syncthreads();
      float M = fmaxf(fmaxf(red[0],red[1]), fmaxf(red[2],red[3]));
      __syncthreads();
      float sloc = 0.f;
      for (int i2 = tid; i2 < n; i2 += NT){ float w = expf(scl[i2]-M); scl[i2]=w; sloc += w; }
      sloc = wredsum(sloc);
      if ((tid&63)==0) red[tid>>6] = sloc;
      __syncthreads();
      float S = red[0]+red[1]+red[2]+red[3];
      float a8[8] = {0,0,0,0,0,0,0,0};
      int ii = wv;
      for (; ii < ncap; ii += 4){
        s8 e0 = *(const s8*)(eL + (size_t)ii*Hd + l*8);
        float w0 = scl[ii];
        #pragma unroll
        for (int j=0;j<8;j++) a8[j] += w0*bf2f((u16)e0[j]);
      }
      for (; ii < n; ii += 4){
        s8 e0 = *(const s8*)(egl + (size_t)ii*Hd + l*8);
        float w0 = scl[ii];
        #pragma unroll
        for (int j=0;j<8;j++) a8[j] += w0*bf2f((u16)e0[j]);
      }
      { f4 v0 = {a8[0],a8[1],a8[2],a8[3]}, v1 = {a8[4],a8[5],a8[6],a8[7]};
        *(f4*)(part + wv*512 + l*8)     = v0;
        *(f4*)(part + wv*512 + l*8 + 4) = v1; }
      __syncthreads();
      {
        int h0 = 2*tid;
        float a0 = part[h0] + part[512+h0] + part[1024+h0] + part[1536+h0];
        float a1 = part[h0+1] + part[512+h0+1] + part[1024+h0+1] + part[1536+h0+1];
        st32a(pacc16 + (size_t)(rowA*2+halfA)*Hd + h0, (u32)f2bf(a0) | ((u32)f2bf(a1) << 16));
        if (tid == 0){
          union { u64 q; float f[2]; } pk; pk.f[0]=M; pk.f[1]=S;
          st64a(pms + rowA*2 + halfA, pk.q);
        }
      }
    }
    RGB();
  }

  // ================= epilogue =================
  const int TL = Le-2;   // 510
  // E1: Vnew_{510} + tanh (all WGs)
  {
    if (tid < 16){
      union { u64 q; float f[2]; } uA, uB;
      uA.q = ld64a(pms + (rg*16+tid)*2 + 0);
      uB.q = ld64a(pms + (rg*16+tid)*2 + 1);
      float M = fmaxf(uA.f[0], uB.f[0]);
      float eA = (uA.f[0] > -1e29f) ? expf(uA.f[0]-M) : 0.f;
      float eB = (uB.f[0] > -1e29f) ? expf(uB.f[0]-M) : 0.f;
      float den = uA.f[1]*eA + uB.f[1]*eB;
      sc2[tid*2]   = eA/den;
      sc2[tid*2+1] = eB/den;
    }
    __syncthreads();
    const float scA = sc2[(l&15)*2], scB = sc2[(l&15)*2+1];
    const u16* h5 = hbf + (size_t)((TL+1)&1)*Bv*Hd;
    const u16* pA = pacc16 + (size_t)(ar*2+0)*Hd;
    const u16* pB = pacc16 + (size_t)(ar*2+1)*Hd;
    const int colc = cg*16 + (l&15);
    f4 vac = {0,0,0,0};
    #pragma unroll
    for (int j = 0; j < 8; j++){
      int kv = k2*16 + j*2 + n2;
      s8 af;
      if (kv < 16) af = ld16a(h5 + (size_t)ar*Hd + kv*32 + kl);
      else {
        s8 va = ld16a(pA + (kv-16)*32 + kl);
        s8 vb = ld16a(pB + (kv-16)*32 + kl);
        #pragma unroll
        for (int q = 0; q < 8; q++)
          af[q] = (short)f2bf(scA*bf2f((u16)va[q]) + scB*bf2f((u16)vb[q]));
      }
      vac = MM(af, *(const s8*)(outw + (size_t)colc*1024 + kv*32 + kl), vac);
    }
    #pragma unroll
    for (int r = 0; r < 4; r++)
      vex[wv*256 + (((l>>4)<<2)+r)*16 + (l&15)] = vac[r];
    __syncthreads();
    {
      int row = tid >> 4, u = tid & 15;
      int gb = cg*16 + u;
      float v = vex[row*16+u] + vex[256+row*16+u] + vex[512+row*16+u]
              + vex[768+row*16+u] + p.outb[gb];
      u32 tb2 = f2bf(tanhf(v));
      u32 tn2 = __shfl_xor((int)tb2, 1, 64);
      if ((tid & 1) == 0){
        u16* tnw = tnhb + (size_t)(TL&1)*Bv*Hd;
        st32a(tnw + (size_t)(rg*16+row)*Hd + gb, tb2 | (tn2 << 16));
      }
    }
  }
  RGB();
  // E2: CE record for step 510 + combine 509
  {
    CEREC(TL);
    if (halfA == 0 && tid == 0) COMB(TL-1);
  }
  RGB();
  // E3: combine step 510, then accumulate loss
  {
    if (halfA == 0 && tid == 0){
      COMB(TL);
      atomicAdd(losp + 0, accN);
      atomicAdd(losp + 1, accC);
    }
  }
  GBall();
  if (wg == 0 && tid == 0) p.out[0] = losp[0] / fmaxf(losp[1], 1.f);
}

extern "C" void kernel_launch(void* const* d_in, const int* in_sizes, int n_in,
                              void* d_out, int out_size, void* d_ws, size_t ws_size,
                              hipStream_t stream)
{
  hipFuncSetAttribute(reinterpret_cast<const void*>(k_main),
                      hipFuncAttributeMaxDynamicSharedMemorySize, SM_BYTES);
  hipMemsetAsync(d_ws, 0, 4096, stream);

  P prm;
  prm.C    = (const float*)d_in[0];
  prm.Cpad = (const int*)  d_in[1];
  prm.E    = (const int*)  d_in[2];
  prm.Eemb = (const float*)d_in[3];
  prm.eWih = (const float*)d_in[4];
  prm.eWhh = (const float*)d_in[5];
  prm.ebih = (const float*)d_in[6];
  prm.ebhh = (const float*)d_in[7];
  prm.dWih = (const float*)d_in[8];
  prm.dWhh = (const float*)d_in[9];
  prm.dbih = (const float*)d_in[10];
  prm.dbhh = (const float*)d_in[11];
  prm.attW = (const float*)d_in[12];
  prm.outW = (const float*)d_in[13];
  prm.outb = (const float*)d_in[14];
  prm.vocW = (const float*)d_in[15];
  prm.vocb = (const float*)d_in[16];
  prm.ws   = (char*)d_ws;
  prm.out  = (float*)d_out;

  k_main<<<dim3(NWG), dim3(NT), SM_BYTES, stream>>>(prm);
}